// Round 13
// baseline (361.801 us; speedup 1.0000x reference)
//
#include <hip/hip_runtime.h>
#include <hip/hip_bf16.h>
#include <math.h>

// Dims (compile-time constants for this problem)
#define Bb 2
#define Tt 1024
#define Dd 512
#define Hh 8
#define Kk 64
#define Vv 64
#define BT (Bb*Tt)          // 2048
#define HK (Hh*Kk)          // 512

// hyperparams
#define B1c 0.9f
#define B2c 0.999f
#define LRc 1e-3f
#define SCALEc 0.125f       // 64^-0.5

// ---------------------------------------------------------------------------
// fp32 tiled GEMM: C[M,N] = A[M,K] @ W[K,N], 128x128 tile, 8x8 micro-tile.
// R12: 64^2 tiles were traffic-bound (~64MB redundant reads/GEMM). 128^2
// halves per-block traffic and doubles fma:ld to 64:16.
// ---------------------------------------------------------------------------
__device__ __forceinline__ void gemm_body(const float* __restrict__ A,
                                          const float* __restrict__ Bm,
                                          float* __restrict__ C) {
  constexpr int N = 512, Kd = 512;
  __shared__ float As[16][132];   // [k][m], 132*4B rows stay 16B-aligned
  __shared__ float Bs[16][132];   // [k][n]
  const int tid = threadIdx.x;
  const int bm = blockIdx.x * 128;
  const int bn = blockIdx.y * 128;
  // staging A: thread -> row tid>>1, k-col group (tid&1)*8
  const int ar  = tid >> 1;
  const int akc = (tid & 1) * 8;
  // staging B: thread -> k-row tid>>4, n-col group (tid&15)*8
  const int bk  = tid >> 4;
  const int bnc = (tid & 15) * 8;
  // compute: 8x8 per thread
  const int tr = (tid >> 4) * 8;
  const int tc = (tid & 15) * 8;

  float acc[8][8] = {};
  for (int k0 = 0; k0 < Kd; k0 += 16) {
    float4 a0 = *(const float4*)(A + (size_t)(bm + ar) * Kd + k0 + akc);
    float4 a1 = *(const float4*)(A + (size_t)(bm + ar) * Kd + k0 + akc + 4);
    float4 b0 = *(const float4*)(Bm + (size_t)(k0 + bk) * N + bn + bnc);
    float4 b1 = *(const float4*)(Bm + (size_t)(k0 + bk) * N + bn + bnc + 4);
    __syncthreads();
    As[akc + 0][ar] = a0.x;  As[akc + 1][ar] = a0.y;
    As[akc + 2][ar] = a0.z;  As[akc + 3][ar] = a0.w;
    As[akc + 4][ar] = a1.x;  As[akc + 5][ar] = a1.y;
    As[akc + 6][ar] = a1.z;  As[akc + 7][ar] = a1.w;
    *(float4*)&Bs[bk][bnc]     = b0;
    *(float4*)&Bs[bk][bnc + 4] = b1;
    __syncthreads();
#pragma unroll
    for (int kk = 0; kk < 16; ++kk) {
      float4 x0 = *(const float4*)&As[kk][tr];
      float4 x1 = *(const float4*)&As[kk][tr + 4];
      float4 y0 = *(const float4*)&Bs[kk][tc];
      float4 y1 = *(const float4*)&Bs[kk][tc + 4];
      const float ai[8] = {x0.x, x0.y, x0.z, x0.w, x1.x, x1.y, x1.z, x1.w};
      const float bj[8] = {y0.x, y0.y, y0.z, y0.w, y1.x, y1.y, y1.z, y1.w};
#pragma unroll
      for (int i = 0; i < 8; ++i)
#pragma unroll
        for (int j = 0; j < 8; ++j) acc[i][j] = fmaf(ai[i], bj[j], acc[i][j]);
    }
  }
#pragma unroll
  for (int i = 0; i < 8; ++i) {
    float4 o0 = {acc[i][0], acc[i][1], acc[i][2], acc[i][3]};
    float4 o1 = {acc[i][4], acc[i][5], acc[i][6], acc[i][7]};
    *(float4*)(C + (size_t)(bm + tr + i) * N + bn + tc)     = o0;
    *(float4*)(C + (size_t)(bm + tr + i) * N + bn + tc + 4) = o1;
  }
}

__global__ __launch_bounds__(256) void gemm3_kernel(
    const float* __restrict__ x,
    const float* __restrict__ Wq, const float* __restrict__ Wk,
    const float* __restrict__ Wv,
    float* __restrict__ qp, float* __restrict__ kp, float* __restrict__ vp) {
  const float* W; float* Cp;
  if (blockIdx.z == 0)      { W = Wq; Cp = qp; }
  else if (blockIdx.z == 1) { W = Wk; Cp = kp; }
  else                      { W = Wv; Cp = vp; }
  gemm_body(x, W, Cp);
}

__global__ __launch_bounds__(256) void gemm1_kernel(
    const float* __restrict__ A, const float* __restrict__ W,
    float* __restrict__ C) {
  gemm_body(A, W, C);
}

// ---------------------------------------------------------------------------
// beta = sigmoid(x @ Wb), Wb:[512,8] -> beta:[B*T,8]
// ---------------------------------------------------------------------------
__global__ __launch_bounds__(256) void beta_kernel(const float* __restrict__ x,
                                                   const float* __restrict__ Wb,
                                                   float* __restrict__ beta) {
  int gid = blockIdx.x * blockDim.x + threadIdx.x;  // 0 .. 16383
  int bt = gid >> 3, h = gid & 7;
  const float* xr = x + (size_t)bt * Dd;
  float s = 0.f;
  for (int d = 0; d < Dd; ++d) s += xr[d] * Wb[d * Hh + h];
  beta[gid] = 1.f / (1.f + expf(-s));
}

// ---------------------------------------------------------------------------
// causal depthwise conv(4) + SiLU (+ optional L2 norm over K, + scale for q)
// ---------------------------------------------------------------------------
__global__ __launch_bounds__(256) void conv_kernel(
    const float* __restrict__ qp, const float* __restrict__ kp,
    const float* __restrict__ vp,
    const float* __restrict__ cwq, const float* __restrict__ cwk,
    const float* __restrict__ cwv,
    float* __restrict__ qc, float* __restrict__ kc, float* __restrict__ vc) {
  const int mode = blockIdx.z;
  const float* pre; const float* cw; float* post;
  if (mode == 0)      { pre = qp; cw = cwq; post = qc; }
  else if (mode == 1) { pre = kp; cw = cwk; post = kc; }
  else                { pre = vp; cw = cwv; post = vc; }

  const int idx = blockIdx.x * 4 + (threadIdx.x >> 6);   // (b,t,h) id, 0..16383
  const int lane = threadIdx.x & 63;
  const int b = idx >> 13;           // /(T*H)
  const int th = idx & 8191;
  const int t = th >> 3;
  const int h = th & 7;
  const int ch = h * 64 + lane;

  float y = 0.f;
#pragma unroll
  for (int i = 0; i < 4; ++i) {
    int tt = t + i - 3;
    if (tt >= 0)
      y += pre[((size_t)(b * Tt + tt)) * HK + ch] * cw[ch * 4 + i];
  }
  // SiLU
  y = y / (1.f + expf(-y));
  if (mode < 2) {
    float ss = y * y;
#pragma unroll
    for (int off = 32; off; off >>= 1) ss += __shfl_xor(ss, off, 64);
    y *= rsqrtf(ss + 1e-6f);
    if (mode == 0) y *= SCALEc;
  }
  post[((size_t)(b * Tt + t)) * HK + ch] = y;
}

// ---------------------------------------------------------------------------
// All-DPP 16-lane butterfly add stage
// ---------------------------------------------------------------------------
template <int CTRL>
__device__ __forceinline__ float dpp_add(float v) {
  int y = __builtin_amdgcn_update_dpp(0, __float_as_int(v), CTRL, 0xF, 0xF, true);
  return v + __int_as_float(y);
}

// ---------------------------------------------------------------------------
// sequential IVON delta-rule scan — pipelined reduces.
//
// R12 model: issue ~200cy + cross-lane stalls 8x~20cy + head ~40 = ~400cy/step.
// Key fix: after S_{s+1}, BOTH o_s = q_s.S and pred_{s+1} = k_{s+1}.S are
// computable; their 4-stage DPP chains are interleaved op-by-op so each ~20cy
// stall is covered by the other chain. pred carries in a register across
// steps/tiles (pred_0 = 0, exact same arithmetic as before).
//
// Staging restructure (so k_{s+1} exists at tile boundaries): tile t+1 is
// ds_written into the other buffer BEFORE computing tile t; its global loads
// were issued one full tile earlier (~6000cy in flight). 2 barriers/tile.
// Layout (R12): W=16 lanes/col, 4 k/lane, 4 cols/wave; 64 blocks x 4 waves.
// Scaled state (exact): G=10g, H=1000h, lrb=0.1*LRc*beta.
// ---------------------------------------------------------------------------
#define TC 16           // steps per LDS tile
#define NT (Tt / TC)    // 64 tiles

__global__ __launch_bounds__(256) void scan_kernel(
    const float* __restrict__ qc, const float* __restrict__ kc,
    const float* __restrict__ vc, const float* __restrict__ beta,
    float* __restrict__ o) {
  __shared__ float4 ks[2][TC][16];   // k[4g..4g+3] per group
  __shared__ float4 qs[2][TC][16];
  __shared__ float2 vb[2][TC][16];   // {v[col], lrb} per column

  const int tid  = threadIdx.x;       // 0..255
  const int lane = tid & 63;
  const int w    = tid >> 6;          // wave 0..3
  const int g    = lane & 15;         // k-group: holds k = 4g..4g+3
  const int cgrp = lane >> 4;         // column group within wave 0..3
  const int bid  = blockIdx.x;        // 0..63
  const int vq   = bid >> 4;          // 0..3  (column 16-group)
  const int bh   = bid & 15;          // bid%8 == bh%8 -> XCD affinity
  const int b = bh >> 3, h = bh & 7;
  const int colbase = vq * 16;
  const int cc = w * 4 + cgrp;        // column within block 0..15
  const int v  = colbase + cc;        // global v column 0..63

  const size_t base2 = ((size_t)b * Tt) * HK + h * 64;
  const float* bp = beta + ((size_t)b * Tt) * Hh + h;
  float* op = o + base2 + v;

  const int sr = tid >> 4;            // staging step row 0..15
  const int sg = tid & 15;            // staging group / v column

  // ---- prologue: stage tile 0 directly into buffer 0 ----
  {
    float4 k4 = *(const float4*)(kc + base2 + (size_t)sr * HK + sg * 4);
    float4 q4 = *(const float4*)(qc + base2 + (size_t)sr * HK + sg * 4);
    float  vv = vc[base2 + (size_t)sr * HK + colbase + sg];
    float  lb = (0.1f * LRc) * bp[(size_t)sr * Hh];
    ks[0][sr][sg] = k4;
    qs[0][sr][sg] = q4;
    vb[0][sr][sg] = make_float2(vv, lb);
  }
  // issue tile 1's global loads (written at iteration 0)
  float4 nk = *(const float4*)(kc + base2 + (size_t)(TC + sr) * HK + sg * 4);
  float4 nq = *(const float4*)(qc + base2 + (size_t)(TC + sr) * HK + sg * 4);
  float  nv = vc[base2 + (size_t)(TC + sr) * HK + colbase + sg];
  float  nb = (0.1f * LRc) * bp[(size_t)(TC + sr) * Hh];
  __syncthreads();

  float S0 = 0, S1 = 0, S2 = 0, S3 = 0;
  float G0 = 0, G1 = 0, G2 = 0, G3 = 0;
  float H0 = 0, H1 = 0, H2 = 0, H3 = 0;
  float pred = 0.f;                    // pred_0 = k_0 . S_0 = 0

  for (int tile = 0; tile < NT; ++tile) {
    const int cur = tile & 1, oth = cur ^ 1;
    const int t0 = tile * TC;

    // write tile t+1 (regs, loaded one tile ago) into the other buffer
    if (tile + 1 < NT) {
      ks[oth][sr][sg] = nk;
      qs[oth][sr][sg] = nq;
      vb[oth][sr][sg] = make_float2(nv, nb);
    }
    __syncthreads();   // tile t+1 visible (boundary k); gates prior reads too

    // issue tile t+2's global loads (consumed next iteration)
    if (tile + 2 < NT) {
      const int tn = (tile + 2) * TC;
      nk = *(const float4*)(kc + base2 + (size_t)(tn + sr) * HK + sg * 4);
      nq = *(const float4*)(qc + base2 + (size_t)(tn + sr) * HK + sg * 4);
      nv = vc[base2 + (size_t)(tn + sr) * HK + colbase + sg];
      nb = (0.1f * LRc) * bp[(size_t)(tn + sr) * Hh];
    }

    // 16 steps from buffer cur; boundary k_{s+1} from buffer oth row 0
#pragma unroll
    for (int s = 0; s < TC; ++s) {
      const float4 kv = ks[cur][s][g];
      const float4 qv = qs[cur][s][g];
      const float2 vbc = vb[cur][s][cc];
      const float4 k1 = (s + 1 < TC) ? ks[cur][s + 1][g] : ks[oth][0][g];

      const float diff = pred - vbc.x;
      const float lrb = vbc.y;
      const float gr0 = kv.x * diff;
      const float gr1 = kv.y * diff;
      const float gr2 = kv.z * diff;
      const float gr3 = kv.w * diff;
      G0 = fmaf(B1c, G0, gr0);
      G1 = fmaf(B1c, G1, gr1);
      G2 = fmaf(B1c, G2, gr2);
      G3 = fmaf(B1c, G3, gr3);
      H0 = fmaf(B2c, H0, gr0 * gr0);
      H1 = fmaf(B2c, H1, gr1 * gr1);
      H2 = fmaf(B2c, H2, gr2 * gr2);
      H3 = fmaf(B2c, H3, gr3 * gr3);
      S0 = fmaf(-lrb, G0 * __builtin_amdgcn_rcpf(fmaf(H0, 0.001f, 1.0f)), S0);
      S1 = fmaf(-lrb, G1 * __builtin_amdgcn_rcpf(fmaf(H1, 0.001f, 1.0f)), S1);
      S2 = fmaf(-lrb, G2 * __builtin_amdgcn_rcpf(fmaf(H2, 0.001f, 1.0f)), S2);
      S3 = fmaf(-lrb, G3 * __builtin_amdgcn_rcpf(fmaf(H3, 0.001f, 1.0f)), S3);

      // both reduces depend only on the fresh S -> interleave their chains
      float po = fmaf(qv.x, S0, qv.y * S1) + fmaf(qv.z, S2, qv.w * S3);
      float pp = fmaf(k1.x, S0, k1.y * S1) + fmaf(k1.z, S2, k1.w * S3);
      po = dpp_add<0xB1>(po);   pp = dpp_add<0xB1>(pp);
      po = dpp_add<0x4E>(po);   pp = dpp_add<0x4E>(pp);
      po = dpp_add<0x141>(po);  pp = dpp_add<0x141>(pp);
      po = dpp_add<0x140>(po);  pp = dpp_add<0x140>(pp);

      if (g == 0) op[(size_t)(t0 + s) * HK] = po;  // 4 lanes/wave: 1 per col
      pred = pp;                                    // pred_{s+1}, exact
    }
    __syncthreads();   // all reads of both buffers done before next overwrite
  }
}

// ---------------------------------------------------------------------------
// RMSNorm over V=64 (in-place), * rms_w
// ---------------------------------------------------------------------------
__global__ __launch_bounds__(256) void rmsnorm_kernel(float* __restrict__ o,
                                                      const float* __restrict__ rmsw) {
  const int idx = blockIdx.x * 4 + (threadIdx.x >> 6);  // (b,t,h), 0..16383
  const int lane = threadIdx.x & 63;
  float* p = o + (size_t)idx * 64;
  float y = p[lane];
  float ss = y * y;
#pragma unroll
  for (int off = 32; off; off >>= 1) ss += __shfl_xor(ss, off, 64);
  y = y * rsqrtf(ss * (1.f / 64.f) + 1e-5f) * rmsw[lane];
  p[lane] = y;
}

// ---------------------------------------------------------------------------
extern "C" void kernel_launch(void* const* d_in, const int* in_sizes, int n_in,
                              void* d_out, int out_size, void* d_ws, size_t ws_size,
                              hipStream_t stream) {
  const float* x    = (const float*)d_in[0];
  const float* Wq   = (const float*)d_in[1];
  const float* Wk   = (const float*)d_in[2];
  const float* Wv   = (const float*)d_in[3];
  const float* Wb   = (const float*)d_in[4];
  const float* cwq  = (const float*)d_in[5];
  const float* cwk  = (const float*)d_in[6];
  const float* cwv  = (const float*)d_in[7];
  const float* rmsw = (const float*)d_in[8];
  const float* Wo   = (const float*)d_in[9];
  float* out = (float*)d_out;
  float* ws  = (float*)d_ws;

  const size_t SZ = (size_t)BT * HK;   // 1,048,576 floats
  float* qp   = ws;            // pre-conv q   (later reused as scan output)
  float* kp   = ws + 1 * SZ;
  float* vp   = ws + 2 * SZ;
  float* qc   = ws + 3 * SZ;
  float* kc   = ws + 4 * SZ;
  float* vc   = ws + 5 * SZ;
  float* beta = ws + 6 * SZ;   // 16384 floats
  float* on   = qp;            // scan output / rmsnorm in-place (qp dead then)

  // 1. projections q,k,v (128x128 tiles)
  gemm3_kernel<<<dim3(BT / 128, HK / 128, 3), 256, 0, stream>>>(x, Wq, Wk, Wv, qp, kp, vp);
  // 2. beta
  beta_kernel<<<dim3(BT * Hh / 256), 256, 0, stream>>>(x, Wb, beta);
  // 3. conv + silu + l2norm
  conv_kernel<<<dim3(Bb * Tt * Hh / 4, 1, 3), 256, 0, stream>>>(
      qp, kp, vp, cwq, cwk, cwv, qc, kc, vc);
  // 4. sequential scan: 64 blocks x 4 waves; pipelined interleaved reduces
  scan_kernel<<<dim3(Bb * Hh * (Vv / 16)), 256, 0, stream>>>(
      qc, kc, vc, beta, on);
  // 5. RMSNorm (in-place)
  rmsnorm_kernel<<<dim3(Bb * Tt * Hh / 4), 256, 0, stream>>>(on, rmsw);
  // 6. output projection (128x128 tiles)
  gemm1_kernel<<<dim3(BT / 128, HK / 128, 1), 256, 0, stream>>>(on, Wo, out);
}

// Round 14
// 253.738 us; speedup vs baseline: 1.4259x; 1.4259x over previous
//
#include <hip/hip_runtime.h>
#include <hip/hip_bf16.h>
#include <math.h>

// Dims (compile-time constants for this problem)
#define Bb 2
#define Tt 1024
#define Dd 512
#define Hh 8
#define Kk 64
#define Vv 64
#define BT (Bb*Tt)          // 2048
#define HK (Hh*Kk)          // 512

// hyperparams
#define B1c 0.9f
#define B2c 0.999f
#define LRc 1e-3f
#define SCALEc 0.125f       // 64^-0.5

// ---------------------------------------------------------------------------
// fp32 tiled GEMM: C[M,N] = A[M,K] @ W[K,N], M=2048, N=512, K=512
// 64x64 tile, 4x4 micro-tile (proven R12 config; 128^2 regressed: 4-way LDS
// bank conflict from 8-float stride + 2x LDS traffic).
// ---------------------------------------------------------------------------
__device__ __forceinline__ void gemm_body(const float* __restrict__ A,
                                          const float* __restrict__ Bm,
                                          float* __restrict__ C) {
  constexpr int N = 512, Kd = 512;
  __shared__ float As[16][68];   // [k][m], padded
  __shared__ float Bs[16][68];   // [k][n]
  const int tid = threadIdx.x;
  const int bm = blockIdx.x * 64;
  const int bn = blockIdx.y * 64;
  const int tr = (tid >> 4) << 2;       // 0..60
  const int tc = (tid & 15) << 2;       // 0..60
  const int ar = tid >> 2;              // A tile row 0..63
  const int ak = (tid & 3) << 2;        // A tile k-col {0,4,8,12}
  const int bk = tid >> 4;              // B tile k-row 0..15
  const int bn4 = (tid & 15) << 2;      // B tile n-col
  float acc[4][4] = {};
  for (int k0 = 0; k0 < Kd; k0 += 16) {
    float4 av = *(const float4*)(A + (size_t)(bm + ar) * Kd + k0 + ak);
    float4 bv = *(const float4*)(Bm + (size_t)(k0 + bk) * N + bn + bn4);
    __syncthreads();
    As[ak + 0][ar] = av.x;
    As[ak + 1][ar] = av.y;
    As[ak + 2][ar] = av.z;
    As[ak + 3][ar] = av.w;
    *(float4*)&Bs[bk][bn4] = bv;
    __syncthreads();
#pragma unroll
    for (int kk = 0; kk < 16; ++kk) {
      float4 a = *(const float4*)&As[kk][tr];
      float4 b = *(const float4*)&Bs[kk][tc];
      const float ai[4] = {a.x, a.y, a.z, a.w};
      const float bj[4] = {b.x, b.y, b.z, b.w};
#pragma unroll
      for (int i = 0; i < 4; ++i)
#pragma unroll
        for (int j = 0; j < 4; ++j) acc[i][j] = fmaf(ai[i], bj[j], acc[i][j]);
    }
  }
#pragma unroll
  for (int i = 0; i < 4; ++i) {
    float4 o4 = {acc[i][0], acc[i][1], acc[i][2], acc[i][3]};
    *(float4*)(C + (size_t)(bm + tr + i) * N + bn + tc) = o4;
  }
}

__global__ __launch_bounds__(256) void gemm3_kernel(
    const float* __restrict__ x,
    const float* __restrict__ Wq, const float* __restrict__ Wk,
    const float* __restrict__ Wv,
    float* __restrict__ qp, float* __restrict__ kp, float* __restrict__ vp) {
  const float* W; float* Cp;
  if (blockIdx.z == 0)      { W = Wq; Cp = qp; }
  else if (blockIdx.z == 1) { W = Wk; Cp = kp; }
  else                      { W = Wv; Cp = vp; }
  gemm_body(x, W, Cp);
}

__global__ __launch_bounds__(256) void gemm1_kernel(
    const float* __restrict__ A, const float* __restrict__ W,
    float* __restrict__ C) {
  gemm_body(A, W, C);
}

// ---------------------------------------------------------------------------
// beta = sigmoid(x @ Wb), Wb:[512,8] -> beta:[B*T,8]
// ---------------------------------------------------------------------------
__global__ __launch_bounds__(256) void beta_kernel(const float* __restrict__ x,
                                                   const float* __restrict__ Wb,
                                                   float* __restrict__ beta) {
  int gid = blockIdx.x * blockDim.x + threadIdx.x;  // 0 .. 16383
  int bt = gid >> 3, h = gid & 7;
  const float* xr = x + (size_t)bt * Dd;
  float s = 0.f;
  for (int d = 0; d < Dd; ++d) s += xr[d] * Wb[d * Hh + h];
  beta[gid] = 1.f / (1.f + expf(-s));
}

// ---------------------------------------------------------------------------
// causal depthwise conv(4) + SiLU (+ optional L2 norm over K, + scale for q)
// ---------------------------------------------------------------------------
__global__ __launch_bounds__(256) void conv_kernel(
    const float* __restrict__ qp, const float* __restrict__ kp,
    const float* __restrict__ vp,
    const float* __restrict__ cwq, const float* __restrict__ cwk,
    const float* __restrict__ cwv,
    float* __restrict__ qc, float* __restrict__ kc, float* __restrict__ vc) {
  const int mode = blockIdx.z;
  const float* pre; const float* cw; float* post;
  if (mode == 0)      { pre = qp; cw = cwq; post = qc; }
  else if (mode == 1) { pre = kp; cw = cwk; post = kc; }
  else                { pre = vp; cw = cwv; post = vc; }

  const int idx = blockIdx.x * 4 + (threadIdx.x >> 6);   // (b,t,h) id, 0..16383
  const int lane = threadIdx.x & 63;
  const int b = idx >> 13;           // /(T*H)
  const int th = idx & 8191;
  const int t = th >> 3;
  const int h = th & 7;
  const int ch = h * 64 + lane;

  float y = 0.f;
#pragma unroll
  for (int i = 0; i < 4; ++i) {
    int tt = t + i - 3;
    if (tt >= 0)
      y += pre[((size_t)(b * Tt + tt)) * HK + ch] * cw[ch * 4 + i];
  }
  // SiLU
  y = y / (1.f + expf(-y));
  if (mode < 2) {
    float ss = y * y;
#pragma unroll
    for (int off = 32; off; off >>= 1) ss += __shfl_xor(ss, off, 64);
    y *= rsqrtf(ss + 1e-6f);
    if (mode == 0) y *= SCALEc;
  }
  post[((size_t)(b * Tt + t)) * HK + ch] = y;
}

// ---------------------------------------------------------------------------
// All-DPP 16-lane butterfly sum
// ---------------------------------------------------------------------------
template <int CTRL>
__device__ __forceinline__ float dpp_add(float v) {
  int y = __builtin_amdgcn_update_dpp(0, __float_as_int(v), CTRL, 0xF, 0xF, true);
  return v + __int_as_float(y);
}

__device__ __forceinline__ float reduce16(float x) {
  x = dpp_add<0xB1>(x);   // quad_perm(1,0,3,2)
  x = dpp_add<0x4E>(x);   // quad_perm(2,3,0,1)
  x = dpp_add<0x141>(x);  // row_half_mirror
  x = dpp_add<0x140>(x);  // row_mirror
  return x;
}

// ---------------------------------------------------------------------------
// sequential IVON delta-rule scan — R12 structure (170us), instruction-slimmed.
//
// R13 lesson: issue/hazard-bound; chain reordering is a dead end. Cuts here:
//  * rcp (quarter-rate, 4x8cy/step) -> carried-Newton reciprocal r of
//    d=0.001H+1: r' = r*(2 - d'*r). d drifts <=0.1%/step (0.999-EMA), so one
//    Newton holds ~1e-6 rel err; init r=1 exact (H=0). 4 fma + 4 mul, full-rate.
//  * maskless store: post-reduce16 all 16 lanes hold the same o; the 16
//    groups' targets are 16 consecutive floats (one 64B line). All 64 lanes
//    store unconditionally (same value->same addr, deterministic); no exec mask.
//  * serial-fma partials (mul+3fma).
// Layout: W=16 lanes/col, 4 k/lane, 4 cols/wave; 64 blocks x 4 waves;
// LDS 16-step double-buffered tiles, issue-early/write-late, 1-step-ahead
// LDS->reg prefetch. Scaled state (exact): G=10g, H=1000h, lrb=0.1*LRc*beta.
// ---------------------------------------------------------------------------
#define TC 16   // steps per LDS tile

__global__ __launch_bounds__(256) void scan_kernel(
    const float* __restrict__ qc, const float* __restrict__ kc,
    const float* __restrict__ vc, const float* __restrict__ beta,
    float* __restrict__ o) {
  __shared__ float4 ks[2][TC][16];   // k[4g..4g+3] per group
  __shared__ float4 qs[2][TC][16];
  __shared__ float2 vb[2][TC][16];   // {v[col], lrb} per column

  const int tid  = threadIdx.x;       // 0..255
  const int lane = tid & 63;
  const int w    = tid >> 6;          // wave 0..3
  const int g    = lane & 15;         // k-group: holds k = 4g..4g+3
  const int cgrp = lane >> 4;         // column group within wave 0..3
  const int bid  = blockIdx.x;        // 0..63
  const int vq   = bid >> 4;          // 0..3  (column 16-group)
  const int bh   = bid & 15;          // bid%8 == bh%8 -> XCD affinity
  const int b = bh >> 3, h = bh & 7;
  const int colbase = vq * 16;
  const int cc = w * 4 + cgrp;        // column within block 0..15
  const int v  = colbase + cc;        // global v column 0..63

  const size_t base2 = ((size_t)b * Tt) * HK + h * 64;
  const float* bp = beta + ((size_t)b * Tt) * Hh + h;
  float* op = o + base2 + v;

  const int sr = tid >> 4;            // staging step row 0..15
  const int sg = tid & 15;            // staging group / v column

  // ---- prologue: stage tile 0 into buffer 0 ----
  {
    float4 k4 = *(const float4*)(kc + base2 + (size_t)sr * HK + sg * 4);
    float4 q4 = *(const float4*)(qc + base2 + (size_t)sr * HK + sg * 4);
    float  vv = vc[base2 + (size_t)sr * HK + colbase + sg];
    float  lb = (0.1f * LRc) * bp[(size_t)sr * Hh];
    ks[0][sr][sg] = k4;
    qs[0][sr][sg] = q4;
    vb[0][sr][sg] = make_float2(vv, lb);
    __syncthreads();
  }

  float S0 = 0, S1 = 0, S2 = 0, S3 = 0;
  float G0 = 0, G1 = 0, G2 = 0, G3 = 0;
  float H0 = 0, H1 = 0, H2 = 0, H3 = 0;
  float r0 = 1.f, r1 = 1.f, r2 = 1.f, r3 = 1.f;   // carried 1/(0.001H+1)

  for (int tile = 0; tile < Tt / TC; ++tile) {
    const int d = tile & 1;
    const int t0 = tile * TC;
    const int more = (tile + 1 < Tt / TC);
    const int tn = more ? t0 + TC : t0;   // clamped (rewrite, unused)

    // issue next tile's global loads NOW (completion hidden under compute)
    float4 nk = *(const float4*)(kc + base2 + (size_t)(tn + sr) * HK + sg * 4);
    float4 nq = *(const float4*)(qc + base2 + (size_t)(tn + sr) * HK + sg * 4);
    float  nv = vc[base2 + (size_t)(tn + sr) * HK + colbase + sg];
    float  nb = (0.1f * LRc) * bp[(size_t)(tn + sr) * Hh];

    // 16 steps from buffer d; LDS->reg prefetch one step ahead
    float4 kcur = ks[d][0][g];
    float4 qcur = qs[d][0][g];
    float2 vbc  = vb[d][0][cc];
#pragma unroll
    for (int s = 0; s < TC; ++s) {
      float4 knx, qnx; float2 vbn;
      if (s + 1 < TC) {
        knx = ks[d][s + 1][g];
        qnx = qs[d][s + 1][g];
        vbn = vb[d][s + 1][cc];
      }
      const float vv = vbc.x, lrb = vbc.y;

      const float pp = fmaf(kcur.x, S0,
                       fmaf(kcur.y, S1,
                       fmaf(kcur.z, S2, kcur.w * S3)));
      const float pred = reduce16(pp);
      const float diff = pred - vv;

      const float gr0 = kcur.x * diff;
      const float gr1 = kcur.y * diff;
      const float gr2 = kcur.z * diff;
      const float gr3 = kcur.w * diff;
      G0 = fmaf(B1c, G0, gr0);
      G1 = fmaf(B1c, G1, gr1);
      G2 = fmaf(B1c, G2, gr2);
      G3 = fmaf(B1c, G3, gr3);
      H0 = fmaf(B2c, H0, gr0 * gr0);
      H1 = fmaf(B2c, H1, gr1 * gr1);
      H2 = fmaf(B2c, H2, gr2 * gr2);
      H3 = fmaf(B2c, H3, gr3 * gr3);
      // carried-Newton reciprocal of d = 0.001H + 1
      const float d0 = fmaf(H0, 0.001f, 1.0f);
      const float d1 = fmaf(H1, 0.001f, 1.0f);
      const float d2 = fmaf(H2, 0.001f, 1.0f);
      const float d3 = fmaf(H3, 0.001f, 1.0f);
      r0 = r0 * fmaf(-d0, r0, 2.0f);
      r1 = r1 * fmaf(-d1, r1, 2.0f);
      r2 = r2 * fmaf(-d2, r2, 2.0f);
      r3 = r3 * fmaf(-d3, r3, 2.0f);
      S0 = fmaf(-lrb, G0 * r0, S0);
      S1 = fmaf(-lrb, G1 * r1, S1);
      S2 = fmaf(-lrb, G2 * r2, S2);
      S3 = fmaf(-lrb, G3 * r3, S3);

      const float po = fmaf(qcur.x, S0,
                       fmaf(qcur.y, S1,
                       fmaf(qcur.z, S2, qcur.w * S3)));
      const float ro = reduce16(po);
      // maskless store: all 16 lanes of a group write the same value to the
      // same address; 16 groups cover one 64B line. Deterministic.
      op[(size_t)(t0 + s) * HK] = ro;
      if (s + 1 < TC) { kcur = knx; qcur = qnx; vbc = vbn; }
    }

    // write next tile into the other buffer; single barrier per tile
    if (more) {
      ks[d ^ 1][sr][sg] = nk;
      qs[d ^ 1][sr][sg] = nq;
      vb[d ^ 1][sr][sg] = make_float2(nv, nb);
    }
    __syncthreads();
  }
}

// ---------------------------------------------------------------------------
// RMSNorm over V=64 (in-place), * rms_w
// ---------------------------------------------------------------------------
__global__ __launch_bounds__(256) void rmsnorm_kernel(float* __restrict__ o,
                                                      const float* __restrict__ rmsw) {
  const int idx = blockIdx.x * 4 + (threadIdx.x >> 6);  // (b,t,h), 0..16383
  const int lane = threadIdx.x & 63;
  float* p = o + (size_t)idx * 64;
  float y = p[lane];
  float ss = y * y;
#pragma unroll
  for (int off = 32; off; off >>= 1) ss += __shfl_xor(ss, off, 64);
  y = y * rsqrtf(ss * (1.f / 64.f) + 1e-5f) * rmsw[lane];
  p[lane] = y;
}

// ---------------------------------------------------------------------------
extern "C" void kernel_launch(void* const* d_in, const int* in_sizes, int n_in,
                              void* d_out, int out_size, void* d_ws, size_t ws_size,
                              hipStream_t stream) {
  const float* x    = (const float*)d_in[0];
  const float* Wq   = (const float*)d_in[1];
  const float* Wk   = (const float*)d_in[2];
  const float* Wv   = (const float*)d_in[3];
  const float* Wb   = (const float*)d_in[4];
  const float* cwq  = (const float*)d_in[5];
  const float* cwk  = (const float*)d_in[6];
  const float* cwv  = (const float*)d_in[7];
  const float* rmsw = (const float*)d_in[8];
  const float* Wo   = (const float*)d_in[9];
  float* out = (float*)d_out;
  float* ws  = (float*)d_ws;

  const size_t SZ = (size_t)BT * HK;   // 1,048,576 floats
  float* qp   = ws;            // pre-conv q   (later reused as scan output)
  float* kp   = ws + 1 * SZ;
  float* vp   = ws + 2 * SZ;
  float* qc   = ws + 3 * SZ;
  float* kc   = ws + 4 * SZ;
  float* vc   = ws + 5 * SZ;
  float* beta = ws + 6 * SZ;   // 16384 floats
  float* on   = qp;            // scan output / rmsnorm in-place (qp dead then)

  // 1. projections q,k,v (64x64 tiles — proven config)
  gemm3_kernel<<<dim3(BT / 64, HK / 64, 3), 256, 0, stream>>>(x, Wq, Wk, Wv, qp, kp, vp);
  // 2. beta
  beta_kernel<<<dim3(BT * Hh / 256), 256, 0, stream>>>(x, Wb, beta);
  // 3. conv + silu + l2norm
  conv_kernel<<<dim3(Bb * Tt * Hh / 4, 1, 3), 256, 0, stream>>>(
      qp, kp, vp, cwq, cwk, cwv, qc, kc, vc);
  // 4. sequential scan: 64 blocks x 4 waves; slimmed per-step body
  scan_kernel<<<dim3(Bb * Hh * (Vv / 16)), 256, 0, stream>>>(
      qc, kc, vc, beta, on);
  // 5. RMSNorm (in-place)
  rmsnorm_kernel<<<dim3(Bb * Tt * Hh / 4), 256, 0, stream>>>(on, rmsw);
  // 6. output projection (64x64 tiles)
  gemm1_kernel<<<dim3(BT / 64, HK / 64, 1), 256, 0, stream>>>(on, Wo, out);
}

// Round 15
// 253.160 us; speedup vs baseline: 1.4291x; 1.0023x over previous
//
#include <hip/hip_runtime.h>
#include <hip/hip_bf16.h>
#include <math.h>

// Dims (compile-time constants for this problem)
#define Bb 2
#define Tt 1024
#define Dd 512
#define Hh 8
#define Kk 64
#define Vv 64
#define BT (Bb*Tt)          // 2048
#define HK (Hh*Kk)          // 512

// hyperparams
#define B1c 0.9f
#define B2c 0.999f
#define LRc 1e-3f
#define SCALEc 0.125f       // 64^-0.5

// ---------------------------------------------------------------------------
// Cross-lane helpers: all-VALU butterfly stages
// ---------------------------------------------------------------------------
template <int CTRL>
__device__ __forceinline__ float dpp_add(float v) {
  int y = __builtin_amdgcn_update_dpp(0, __float_as_int(v), CTRL, 0xF, 0xF, true);
  return v + __int_as_float(y);
}

typedef unsigned uint2_t __attribute__((ext_vector_type(2)));

__device__ __forceinline__ float xor16_add(float x) {
#if __has_builtin(__builtin_amdgcn_permlane16_swap)
  uint2_t r = __builtin_amdgcn_permlane16_swap(__float_as_uint(x), __float_as_uint(x),
                                               false, false);
  return __uint_as_float(r.x) + __uint_as_float(r.y);
#else
  int y = __builtin_amdgcn_ds_swizzle(__float_as_int(x), 0x401F);  // xor 16
  return x + __int_as_float(y);
#endif
}

__device__ __forceinline__ float xor32_add(float x) {
#if __has_builtin(__builtin_amdgcn_permlane32_swap)
  uint2_t r = __builtin_amdgcn_permlane32_swap(__float_as_uint(x), __float_as_uint(x),
                                               false, false);
  return __uint_as_float(r.x) + __uint_as_float(r.y);
#else
  return x + __shfl_xor(x, 32, 64);
#endif
}

__device__ __forceinline__ float reduce16(float x) {
  x = dpp_add<0xB1>(x);   // quad_perm(1,0,3,2)
  x = dpp_add<0x4E>(x);   // quad_perm(2,3,0,1)
  x = dpp_add<0x141>(x);  // row_half_mirror
  x = dpp_add<0x140>(x);  // row_mirror
  return x;
}

__device__ __forceinline__ float reduce64(float x) {
  x = reduce16(x);
  x = xor16_add(x);
  x = xor32_add(x);
  return x;
}

// ---------------------------------------------------------------------------
// fp32 tiled GEMM: C[M,N] = A[M,K] @ W[K,N], M=2048, N=512, K=512
// 64x64 tile, 4x4 micro-tile. R15: double-buffered LDS (1 barrier/iter) +
// software-pipelined global loads (next tile issued before compute).
// ---------------------------------------------------------------------------
__device__ __forceinline__ void gemm_body(const float* __restrict__ A,
                                          const float* __restrict__ Bm,
                                          float* __restrict__ C) {
  constexpr int N = 512, Kd = 512;
  __shared__ float As[2][16][68];   // [buf][k][m], padded
  __shared__ float Bs[2][16][68];   // [buf][k][n]
  const int tid = threadIdx.x;
  const int bm = blockIdx.x * 64;
  const int bn = blockIdx.y * 64;
  const int tr = (tid >> 4) << 2;       // 0..60
  const int tc = (tid & 15) << 2;       // 0..60
  const int ar = tid >> 2;              // A tile row 0..63
  const int ak = (tid & 3) << 2;        // A tile k-col {0,4,8,12}
  const int bk = tid >> 4;              // B tile k-row 0..15
  const int bn4 = (tid & 15) << 2;      // B tile n-col

  const float* Aptr = A + (size_t)(bm + ar) * Kd + ak;
  const float* Bptr = Bm + (size_t)bk * N + bn + bn4;

  // prologue: stage k0=0 into buffer 0
  {
    float4 av = *(const float4*)(Aptr);
    float4 bv = *(const float4*)(Bptr);
    As[0][ak + 0][ar] = av.x;
    As[0][ak + 1][ar] = av.y;
    As[0][ak + 2][ar] = av.z;
    As[0][ak + 3][ar] = av.w;
    *(float4*)&Bs[0][bk][bn4] = bv;
  }
  __syncthreads();

  float acc[4][4] = {};
  for (int k0 = 0; k0 < Kd; k0 += 16) {
    const int d = (k0 >> 4) & 1;
    const bool more = (k0 + 16 < Kd);
    // issue next tile's global loads (latency hidden under the 256 FMAs)
    float4 av, bv;
    if (more) {
      av = *(const float4*)(Aptr + k0 + 16);
      bv = *(const float4*)(Bptr + (size_t)(k0 + 16) * N);
    }
#pragma unroll
    for (int kk = 0; kk < 16; ++kk) {
      float4 a = *(const float4*)&As[d][kk][tr];
      float4 b = *(const float4*)&Bs[d][kk][tc];
      const float ai[4] = {a.x, a.y, a.z, a.w};
      const float bj[4] = {b.x, b.y, b.z, b.w};
#pragma unroll
      for (int i = 0; i < 4; ++i)
#pragma unroll
        for (int j = 0; j < 4; ++j) acc[i][j] = fmaf(ai[i], bj[j], acc[i][j]);
    }
    if (more) {
      As[d ^ 1][ak + 0][ar] = av.x;
      As[d ^ 1][ak + 1][ar] = av.y;
      As[d ^ 1][ak + 2][ar] = av.z;
      As[d ^ 1][ak + 3][ar] = av.w;
      *(float4*)&Bs[d ^ 1][bk][bn4] = bv;
    }
    __syncthreads();
  }
#pragma unroll
  for (int i = 0; i < 4; ++i) {
    float4 o4 = {acc[i][0], acc[i][1], acc[i][2], acc[i][3]};
    *(float4*)(C + (size_t)(bm + tr + i) * N + bn + tc) = o4;
  }
}

__global__ __launch_bounds__(256) void gemm3_kernel(
    const float* __restrict__ x,
    const float* __restrict__ Wq, const float* __restrict__ Wk,
    const float* __restrict__ Wv,
    float* __restrict__ qp, float* __restrict__ kp, float* __restrict__ vp) {
  const float* W; float* Cp;
  if (blockIdx.z == 0)      { W = Wq; Cp = qp; }
  else if (blockIdx.z == 1) { W = Wk; Cp = kp; }
  else                      { W = Wv; Cp = vp; }
  gemm_body(x, W, Cp);
}

__global__ __launch_bounds__(256) void gemm1_kernel(
    const float* __restrict__ A, const float* __restrict__ W,
    float* __restrict__ C) {
  gemm_body(A, W, C);
}

// ---------------------------------------------------------------------------
// beta = sigmoid(x @ Wb), Wb:[512,8] -> beta:[B*T,8]  (float4-vectorized)
// ---------------------------------------------------------------------------
__global__ __launch_bounds__(256) void beta_kernel(const float* __restrict__ x,
                                                   const float* __restrict__ Wb,
                                                   float* __restrict__ beta) {
  int gid = blockIdx.x * blockDim.x + threadIdx.x;  // 0 .. 16383
  int bt = gid >> 3, h = gid & 7;
  const float4* xr = (const float4*)(x + (size_t)bt * Dd);
  float s = 0.f;
#pragma unroll 4
  for (int d4 = 0; d4 < Dd / 4; ++d4) {
    float4 xv = xr[d4];
    const float* wb = Wb + (d4 * 4) * Hh + h;
    s = fmaf(xv.x, wb[0 * Hh], s);
    s = fmaf(xv.y, wb[1 * Hh], s);
    s = fmaf(xv.z, wb[2 * Hh], s);
    s = fmaf(xv.w, wb[3 * Hh], s);
  }
  beta[gid] = 1.f / (1.f + expf(-s));
}

// ---------------------------------------------------------------------------
// causal depthwise conv(4) + SiLU (+ optional L2 norm over K, + scale for q)
// R15: l2norm reduce via all-VALU DPP/permlane (was 6x ds-__shfl_xor).
// ---------------------------------------------------------------------------
__global__ __launch_bounds__(256) void conv_kernel(
    const float* __restrict__ qp, const float* __restrict__ kp,
    const float* __restrict__ vp,
    const float* __restrict__ cwq, const float* __restrict__ cwk,
    const float* __restrict__ cwv,
    float* __restrict__ qc, float* __restrict__ kc, float* __restrict__ vc) {
  const int mode = blockIdx.z;
  const float* pre; const float* cw; float* post;
  if (mode == 0)      { pre = qp; cw = cwq; post = qc; }
  else if (mode == 1) { pre = kp; cw = cwk; post = kc; }
  else                { pre = vp; cw = cwv; post = vc; }

  const int idx = blockIdx.x * 4 + (threadIdx.x >> 6);   // (b,t,h) id, 0..16383
  const int lane = threadIdx.x & 63;
  const int b = idx >> 13;           // /(T*H)
  const int th = idx & 8191;
  const int t = th >> 3;
  const int h = th & 7;
  const int ch = h * 64 + lane;

  float y = 0.f;
#pragma unroll
  for (int i = 0; i < 4; ++i) {
    int tt = t + i - 3;
    if (tt >= 0)
      y += pre[((size_t)(b * Tt + tt)) * HK + ch] * cw[ch * 4 + i];
  }
  // SiLU
  y = y / (1.f + expf(-y));
  if (mode < 2) {
    float ss = reduce64(y * y);
    y *= rsqrtf(ss + 1e-6f);
    if (mode == 0) y *= SCALEc;
  }
  post[((size_t)(b * Tt + t)) * HK + ch] = y;
}

// ---------------------------------------------------------------------------
// sequential IVON delta-rule scan — R14 winner, UNCHANGED (control).
// W=16 lanes/col, 4 k/lane, 4 cols/wave; LDS 16-step double-buffered tiles;
// carried-Newton reciprocal; maskless store.
// ---------------------------------------------------------------------------
#define TC 16   // steps per LDS tile

__global__ __launch_bounds__(256) void scan_kernel(
    const float* __restrict__ qc, const float* __restrict__ kc,
    const float* __restrict__ vc, const float* __restrict__ beta,
    float* __restrict__ o) {
  __shared__ float4 ks[2][TC][16];   // k[4g..4g+3] per group
  __shared__ float4 qs[2][TC][16];
  __shared__ float2 vb[2][TC][16];   // {v[col], lrb} per column

  const int tid  = threadIdx.x;       // 0..255
  const int lane = tid & 63;
  const int w    = tid >> 6;          // wave 0..3
  const int g    = lane & 15;         // k-group: holds k = 4g..4g+3
  const int cgrp = lane >> 4;         // column group within wave 0..3
  const int bid  = blockIdx.x;        // 0..63
  const int vq   = bid >> 4;          // 0..3  (column 16-group)
  const int bh   = bid & 15;          // bid%8 == bh%8 -> XCD affinity
  const int b = bh >> 3, h = bh & 7;
  const int colbase = vq * 16;
  const int cc = w * 4 + cgrp;        // column within block 0..15
  const int v  = colbase + cc;        // global v column 0..63

  const size_t base2 = ((size_t)b * Tt) * HK + h * 64;
  const float* bp = beta + ((size_t)b * Tt) * Hh + h;
  float* op = o + base2 + v;

  const int sr = tid >> 4;            // staging step row 0..15
  const int sg = tid & 15;            // staging group / v column

  // ---- prologue: stage tile 0 into buffer 0 ----
  {
    float4 k4 = *(const float4*)(kc + base2 + (size_t)sr * HK + sg * 4);
    float4 q4 = *(const float4*)(qc + base2 + (size_t)sr * HK + sg * 4);
    float  vv = vc[base2 + (size_t)sr * HK + colbase + sg];
    float  lb = (0.1f * LRc) * bp[(size_t)sr * Hh];
    ks[0][sr][sg] = k4;
    qs[0][sr][sg] = q4;
    vb[0][sr][sg] = make_float2(vv, lb);
    __syncthreads();
  }

  float S0 = 0, S1 = 0, S2 = 0, S3 = 0;
  float G0 = 0, G1 = 0, G2 = 0, G3 = 0;
  float H0 = 0, H1 = 0, H2 = 0, H3 = 0;
  float r0 = 1.f, r1 = 1.f, r2 = 1.f, r3 = 1.f;   // carried 1/(0.001H+1)

  for (int tile = 0; tile < Tt / TC; ++tile) {
    const int d = tile & 1;
    const int t0 = tile * TC;
    const int more = (tile + 1 < Tt / TC);
    const int tn = more ? t0 + TC : t0;   // clamped (rewrite, unused)

    // issue next tile's global loads NOW (completion hidden under compute)
    float4 nk = *(const float4*)(kc + base2 + (size_t)(tn + sr) * HK + sg * 4);
    float4 nq = *(const float4*)(qc + base2 + (size_t)(tn + sr) * HK + sg * 4);
    float  nv = vc[base2 + (size_t)(tn + sr) * HK + colbase + sg];
    float  nb = (0.1f * LRc) * bp[(size_t)(tn + sr) * Hh];

    // 16 steps from buffer d; LDS->reg prefetch one step ahead
    float4 kcur = ks[d][0][g];
    float4 qcur = qs[d][0][g];
    float2 vbc  = vb[d][0][cc];
#pragma unroll
    for (int s = 0; s < TC; ++s) {
      float4 knx, qnx; float2 vbn;
      if (s + 1 < TC) {
        knx = ks[d][s + 1][g];
        qnx = qs[d][s + 1][g];
        vbn = vb[d][s + 1][cc];
      }
      const float vv = vbc.x, lrb = vbc.y;

      const float pp = fmaf(kcur.x, S0,
                       fmaf(kcur.y, S1,
                       fmaf(kcur.z, S2, kcur.w * S3)));
      const float pred = reduce16(pp);
      const float diff = pred - vv;

      const float gr0 = kcur.x * diff;
      const float gr1 = kcur.y * diff;
      const float gr2 = kcur.z * diff;
      const float gr3 = kcur.w * diff;
      G0 = fmaf(B1c, G0, gr0);
      G1 = fmaf(B1c, G1, gr1);
      G2 = fmaf(B1c, G2, gr2);
      G3 = fmaf(B1c, G3, gr3);
      H0 = fmaf(B2c, H0, gr0 * gr0);
      H1 = fmaf(B2c, H1, gr1 * gr1);
      H2 = fmaf(B2c, H2, gr2 * gr2);
      H3 = fmaf(B2c, H3, gr3 * gr3);
      // carried-Newton reciprocal of d = 0.001H + 1
      const float d0 = fmaf(H0, 0.001f, 1.0f);
      const float d1 = fmaf(H1, 0.001f, 1.0f);
      const float d2 = fmaf(H2, 0.001f, 1.0f);
      const float d3 = fmaf(H3, 0.001f, 1.0f);
      r0 = r0 * fmaf(-d0, r0, 2.0f);
      r1 = r1 * fmaf(-d1, r1, 2.0f);
      r2 = r2 * fmaf(-d2, r2, 2.0f);
      r3 = r3 * fmaf(-d3, r3, 2.0f);
      S0 = fmaf(-lrb, G0 * r0, S0);
      S1 = fmaf(-lrb, G1 * r1, S1);
      S2 = fmaf(-lrb, G2 * r2, S2);
      S3 = fmaf(-lrb, G3 * r3, S3);

      const float po = fmaf(qcur.x, S0,
                       fmaf(qcur.y, S1,
                       fmaf(qcur.z, S2, qcur.w * S3)));
      const float ro = reduce16(po);
      op[(size_t)(t0 + s) * HK] = ro;   // maskless: uniform per 16-group
      if (s + 1 < TC) { kcur = knx; qcur = qnx; vbc = vbn; }
    }

    // write next tile into the other buffer; single barrier per tile
    if (more) {
      ks[d ^ 1][sr][sg] = nk;
      qs[d ^ 1][sr][sg] = nq;
      vb[d ^ 1][sr][sg] = make_float2(nv, nb);
    }
    __syncthreads();
  }
}

// ---------------------------------------------------------------------------
// RMSNorm over V=64 (in-place), * rms_w   (DPP reduce)
// ---------------------------------------------------------------------------
__global__ __launch_bounds__(256) void rmsnorm_kernel(float* __restrict__ o,
                                                      const float* __restrict__ rmsw) {
  const int idx = blockIdx.x * 4 + (threadIdx.x >> 6);  // (b,t,h), 0..16383
  const int lane = threadIdx.x & 63;
  float* p = o + (size_t)idx * 64;
  float y = p[lane];
  float ss = reduce64(y * y);
  y = y * rsqrtf(ss * (1.f / 64.f) + 1e-5f) * rmsw[lane];
  p[lane] = y;
}

// ---------------------------------------------------------------------------
extern "C" void kernel_launch(void* const* d_in, const int* in_sizes, int n_in,
                              void* d_out, int out_size, void* d_ws, size_t ws_size,
                              hipStream_t stream) {
  const float* x    = (const float*)d_in[0];
  const float* Wq   = (const float*)d_in[1];
  const float* Wk   = (const float*)d_in[2];
  const float* Wv   = (const float*)d_in[3];
  const float* Wb   = (const float*)d_in[4];
  const float* cwq  = (const float*)d_in[5];
  const float* cwk  = (const float*)d_in[6];
  const float* cwv  = (const float*)d_in[7];
  const float* rmsw = (const float*)d_in[8];
  const float* Wo   = (const float*)d_in[9];
  float* out = (float*)d_out;
  float* ws  = (float*)d_ws;

  const size_t SZ = (size_t)BT * HK;   // 1,048,576 floats
  float* qp   = ws;            // pre-conv q   (later reused as scan output)
  float* kp   = ws + 1 * SZ;
  float* vp   = ws + 2 * SZ;
  float* qc   = ws + 3 * SZ;
  float* kc   = ws + 4 * SZ;
  float* vc   = ws + 5 * SZ;
  float* beta = ws + 6 * SZ;   // 16384 floats
  float* on   = qp;            // scan output / rmsnorm in-place (qp dead then)

  // 1. projections q,k,v (64x64 tiles, dbuf + pipelined loads)
  gemm3_kernel<<<dim3(BT / 64, HK / 64, 3), 256, 0, stream>>>(x, Wq, Wk, Wv, qp, kp, vp);
  // 2. beta (vectorized)
  beta_kernel<<<dim3(BT * Hh / 256), 256, 0, stream>>>(x, Wb, beta);
  // 3. conv + silu + l2norm (DPP reduce)
  conv_kernel<<<dim3(Bb * Tt * Hh / 4, 1, 3), 256, 0, stream>>>(
      qp, kp, vp, cwq, cwk, cwv, qc, kc, vc);
  // 4. sequential scan (R14 winner, unchanged)
  scan_kernel<<<dim3(Bb * Hh * (Vv / 16)), 256, 0, stream>>>(
      qc, kc, vc, beta, on);
  // 5. RMSNorm (DPP reduce)
  rmsnorm_kernel<<<dim3(Bb * Tt * Hh / 4), 256, 0, stream>>>(on, rmsw);
  // 6. output projection
  gemm1_kernel<<<dim3(BT / 64, HK / 64, 1), 256, 0, stream>>>(on, Wo, out);
}

// Round 16
// 219.965 us; speedup vs baseline: 1.6448x; 1.1509x over previous
//
#include <hip/hip_runtime.h>
#include <hip/hip_bf16.h>
#include <math.h>

// Dims (compile-time constants for this problem)
#define Bb 2
#define Tt 1024
#define Dd 512
#define Hh 8
#define Kk 64
#define Vv 64
#define BT (Bb*Tt)          // 2048
#define HK (Hh*Kk)          // 512

// hyperparams
#define B1c 0.9f
#define B2c 0.999f
#define LRc 1e-3f
#define SCALEc 0.125f       // 64^-0.5

typedef short s8v __attribute__((ext_vector_type(8)));   // 8 bf16 = 4 VGPR
typedef float f4v __attribute__((ext_vector_type(4)));   // MFMA acc

// ---------------------------------------------------------------------------
// bf16 split helpers (RNE)
// ---------------------------------------------------------------------------
__device__ __forceinline__ unsigned short f2bf(float x) {
  unsigned u = __float_as_uint(x);
  u += 0x7FFFu + ((u >> 16) & 1u);
  return (unsigned short)(u >> 16);
}
__device__ __forceinline__ float bf2f(unsigned short h) {
  return __uint_as_float((unsigned)h << 16);
}

// ---------------------------------------------------------------------------
// Cross-lane helpers: all-VALU butterfly stages
// ---------------------------------------------------------------------------
template <int CTRL>
__device__ __forceinline__ float dpp_add(float v) {
  int y = __builtin_amdgcn_update_dpp(0, __float_as_int(v), CTRL, 0xF, 0xF, true);
  return v + __int_as_float(y);
}

typedef unsigned uint2_t __attribute__((ext_vector_type(2)));

__device__ __forceinline__ float xor16_add(float x) {
#if __has_builtin(__builtin_amdgcn_permlane16_swap)
  uint2_t r = __builtin_amdgcn_permlane16_swap(__float_as_uint(x), __float_as_uint(x),
                                               false, false);
  return __uint_as_float(r.x) + __uint_as_float(r.y);
#else
  int y = __builtin_amdgcn_ds_swizzle(__float_as_int(x), 0x401F);
  return x + __int_as_float(y);
#endif
}

__device__ __forceinline__ float xor32_add(float x) {
#if __has_builtin(__builtin_amdgcn_permlane32_swap)
  uint2_t r = __builtin_amdgcn_permlane32_swap(__float_as_uint(x), __float_as_uint(x),
                                               false, false);
  return __uint_as_float(r.x) + __uint_as_float(r.y);
#else
  return x + __shfl_xor(x, 32, 64);
#endif
}

__device__ __forceinline__ float reduce16(float x) {
  x = dpp_add<0xB1>(x);
  x = dpp_add<0x4E>(x);
  x = dpp_add<0x141>(x);
  x = dpp_add<0x140>(x);
  return x;
}

__device__ __forceinline__ float reduce64(float x) {
  x = reduce16(x);
  x = xor16_add(x);
  x = xor32_add(x);
  return x;
}

// ---------------------------------------------------------------------------
// cvt_x: fp32 [M][512] -> hi/lo bf16 [M][512] (row-major)
// ---------------------------------------------------------------------------
__global__ __launch_bounds__(256) void cvt_x_kernel(
    const float* __restrict__ x, unsigned short* __restrict__ hi,
    unsigned short* __restrict__ lo) {
  const int i = (blockIdx.x * 256 + threadIdx.x) * 8;
  float4 a = *(const float4*)(x + i);
  float4 b = *(const float4*)(x + i + 4);
  const float v[8] = {a.x, a.y, a.z, a.w, b.x, b.y, b.z, b.w};
  union { unsigned short u[8]; uint4 q; } ph, pl;
#pragma unroll
  for (int j = 0; j < 8; ++j) {
    unsigned short h = f2bf(v[j]);
    ph.u[j] = h;
    pl.u[j] = f2bf(v[j] - bf2f(h));
  }
  *(uint4*)(hi + i) = ph.q;
  *(uint4*)(lo + i) = pl.q;
}

// ---------------------------------------------------------------------------
// cvt_w: W [512 k][512 n] fp32 -> hi/lo bf16 TRANSPOSED [n][k].
// blockIdx.z selects matrix; out offset z*512*512.
// ---------------------------------------------------------------------------
__global__ __launch_bounds__(256) void cvt_w_kernel(
    const float* __restrict__ W0, const float* __restrict__ W1,
    const float* __restrict__ W2,
    unsigned short* __restrict__ hib, unsigned short* __restrict__ lob) {
  __shared__ float Ts[64][65];
  const int z = blockIdx.z;
  const float* W = (z == 0) ? W0 : (z == 1) ? W1 : W2;
  unsigned short* hi = hib + (size_t)z * 512 * 512;
  unsigned short* lo = lob + (size_t)z * 512 * 512;
  const int tk = blockIdx.x * 64;
  const int tn = blockIdx.y * 64;
  const int r  = threadIdx.x >> 2;
  const int cg = threadIdx.x & 3;
#pragma unroll
  for (int j = 0; j < 4; ++j) {
    float4 v = *(const float4*)(W + (size_t)(tk + r) * 512 + tn + cg * 16 + j * 4);
    Ts[r][cg * 16 + j * 4 + 0] = v.x;
    Ts[r][cg * 16 + j * 4 + 1] = v.y;
    Ts[r][cg * 16 + j * 4 + 2] = v.z;
    Ts[r][cg * 16 + j * 4 + 3] = v.w;
  }
  __syncthreads();
  union { unsigned short u[16]; uint4 q[2]; } ph, pl;
#pragma unroll
  for (int j = 0; j < 16; ++j) {
    float v = Ts[cg * 16 + j][r];
    unsigned short h = f2bf(v);
    ph.u[j] = h;
    pl.u[j] = f2bf(v - bf2f(h));
  }
  const size_t ob = (size_t)(tn + r) * 512 + tk + cg * 16;
  *(uint4*)(hi + ob) = ph.q[0];
  *(uint4*)(hi + ob + 8) = ph.q[1];
  *(uint4*)(lo + ob) = pl.q[0];
  *(uint4*)(lo + ob + 8) = pl.q[1];
}

// ---------------------------------------------------------------------------
// split-bf16 MFMA GEMM: C[M,512] = A[M,512] @ W[512,512]
// A as hi/lo bf16 [m][k]; W as hi/lo bf16 TRANSPOSED [n][k].
// product = ahi*bhi + ahi*blo + alo*bhi (3x mfma_f32_16x16x32_bf16).
// 64x64 tile, 4 waves: wave w = rows [16w,16w+16), 4 col-tiles.
// Frag layout (m89-verified family): A row=lane&15, k=8*(lane>>4)+i;
// B col=lane&15, same k; C/D col=lane&15, row=(lane>>4)*4+reg.
// LDS rows padded to 40 ushorts (80B stride -> 2-way bank alias, free).
// ---------------------------------------------------------------------------
__device__ __forceinline__ void gemm_mfma_body(
    const unsigned short* __restrict__ Ahi, const unsigned short* __restrict__ Alo,
    const unsigned short* __restrict__ Bhi, const unsigned short* __restrict__ Blo,
    float* __restrict__ C) {
  __shared__ unsigned short Ah[64][40], Al[64][40], Bh[64][40], Bl[64][40];
  const int tid = threadIdx.x;
  const int bm = blockIdx.x * 64;
  const int bn = blockIdx.y * 64;
  const int srow = tid >> 2;            // 0..63
  const int skoff = (tid & 3) * 8;      // 0,8,16,24
  const int l = tid & 63, w = tid >> 6;
  const int arow = 16 * 0 + (l & 15) + 16 * w;  // wave's row
  const int koff = (l >> 4) * 8;

  const unsigned short* pAh = Ahi + (size_t)(bm + srow) * 512 + skoff;
  const unsigned short* pAl = Alo + (size_t)(bm + srow) * 512 + skoff;
  const unsigned short* pBh = Bhi + (size_t)(bn + srow) * 512 + skoff;
  const unsigned short* pBl = Blo + (size_t)(bn + srow) * 512 + skoff;

  f4v acc0 = {0.f, 0.f, 0.f, 0.f}, acc1 = acc0, acc2 = acc0, acc3 = acc0;

  uint4 rah = *(const uint4*)(pAh);
  uint4 ral = *(const uint4*)(pAl);
  uint4 rbh = *(const uint4*)(pBh);
  uint4 rbl = *(const uint4*)(pBl);

  for (int k0 = 0; k0 < 512; k0 += 32) {
    __syncthreads();                    // prior iter's frag reads done
    *(uint4*)&Ah[srow][skoff] = rah;
    *(uint4*)&Al[srow][skoff] = ral;
    *(uint4*)&Bh[srow][skoff] = rbh;
    *(uint4*)&Bl[srow][skoff] = rbl;
    __syncthreads();
    if (k0 + 32 < 512) {                // prefetch next (in flight over MFMAs)
      rah = *(const uint4*)(pAh + k0 + 32);
      ral = *(const uint4*)(pAl + k0 + 32);
      rbh = *(const uint4*)(pBh + k0 + 32);
      rbl = *(const uint4*)(pBl + k0 + 32);
    }
    const s8v ah = *(const s8v*)&Ah[arow][koff];
    const s8v al = *(const s8v*)&Al[arow][koff];
#pragma unroll
    for (int c = 0; c < 4; ++c) {
      const s8v bh = *(const s8v*)&Bh[16 * c + (l & 15)][koff];
      const s8v bl = *(const s8v*)&Bl[16 * c + (l & 15)][koff];
      f4v* acc = (c == 0) ? &acc0 : (c == 1) ? &acc1 : (c == 2) ? &acc2 : &acc3;
      *acc = __builtin_amdgcn_mfma_f32_16x16x32_bf16(al, bh, *acc, 0, 0, 0);
      *acc = __builtin_amdgcn_mfma_f32_16x16x32_bf16(ah, bl, *acc, 0, 0, 0);
      *acc = __builtin_amdgcn_mfma_f32_16x16x32_bf16(ah, bh, *acc, 0, 0, 0);
    }
  }

  const int crow = bm + 16 * w + (l >> 4) * 4;
  const int ccol = bn + (l & 15);
#pragma unroll
  for (int i = 0; i < 4; ++i) {
    C[(size_t)(crow + i) * 512 + ccol + 0]  = acc0[i];
    C[(size_t)(crow + i) * 512 + ccol + 16] = acc1[i];
    C[(size_t)(crow + i) * 512 + ccol + 32] = acc2[i];
    C[(size_t)(crow + i) * 512 + ccol + 48] = acc3[i];
  }
}

__global__ __launch_bounds__(256) void gemm3_mfma_kernel(
    const unsigned short* __restrict__ xhi, const unsigned short* __restrict__ xlo,
    const unsigned short* __restrict__ whi, const unsigned short* __restrict__ wlo,
    float* __restrict__ qp, float* __restrict__ kp, float* __restrict__ vp) {
  const int z = blockIdx.z;
  float* Cp = (z == 0) ? qp : (z == 1) ? kp : vp;
  gemm_mfma_body(xhi, xlo, whi + (size_t)z * 512 * 512, wlo + (size_t)z * 512 * 512, Cp);
}

__global__ __launch_bounds__(256) void gemm1_mfma_kernel(
    const unsigned short* __restrict__ ahi, const unsigned short* __restrict__ alo,
    const unsigned short* __restrict__ whi, const unsigned short* __restrict__ wlo,
    float* __restrict__ C) {
  gemm_mfma_body(ahi, alo, whi, wlo, C);
}

// ---------------------------------------------------------------------------
// beta = sigmoid(x @ Wb) (float4-vectorized)
// ---------------------------------------------------------------------------
__global__ __launch_bounds__(256) void beta_kernel(const float* __restrict__ x,
                                                   const float* __restrict__ Wb,
                                                   float* __restrict__ beta) {
  int gid = blockIdx.x * blockDim.x + threadIdx.x;
  int bt = gid >> 3, h = gid & 7;
  const float4* xr = (const float4*)(x + (size_t)bt * Dd);
  float s = 0.f;
#pragma unroll 4
  for (int d4 = 0; d4 < Dd / 4; ++d4) {
    float4 xv = xr[d4];
    const float* wb = Wb + (d4 * 4) * Hh + h;
    s = fmaf(xv.x, wb[0 * Hh], s);
    s = fmaf(xv.y, wb[1 * Hh], s);
    s = fmaf(xv.z, wb[2 * Hh], s);
    s = fmaf(xv.w, wb[3 * Hh], s);
  }
  beta[gid] = 1.f / (1.f + expf(-s));
}

// ---------------------------------------------------------------------------
// causal depthwise conv(4) + SiLU (+ optional L2 norm + scale)
// ---------------------------------------------------------------------------
__global__ __launch_bounds__(256) void conv_kernel(
    const float* __restrict__ qp, const float* __restrict__ kp,
    const float* __restrict__ vp,
    const float* __restrict__ cwq, const float* __restrict__ cwk,
    const float* __restrict__ cwv,
    float* __restrict__ qc, float* __restrict__ kc, float* __restrict__ vc) {
  const int mode = blockIdx.z;
  const float* pre; const float* cw; float* post;
  if (mode == 0)      { pre = qp; cw = cwq; post = qc; }
  else if (mode == 1) { pre = kp; cw = cwk; post = kc; }
  else                { pre = vp; cw = cwv; post = vc; }

  const int idx = blockIdx.x * 4 + (threadIdx.x >> 6);
  const int lane = threadIdx.x & 63;
  const int b = idx >> 13;
  const int th = idx & 8191;
  const int t = th >> 3;
  const int h = th & 7;
  const int ch = h * 64 + lane;

  float y = 0.f;
#pragma unroll
  for (int i = 0; i < 4; ++i) {
    int tt = t + i - 3;
    if (tt >= 0)
      y += pre[((size_t)(b * Tt + tt)) * HK + ch] * cw[ch * 4 + i];
  }
  y = y / (1.f + expf(-y));
  if (mode < 2) {
    float ss = reduce64(y * y);
    y *= rsqrtf(ss + 1e-6f);
    if (mode == 0) y *= SCALEc;
  }
  post[((size_t)(b * Tt + t)) * HK + ch] = y;
}

// ---------------------------------------------------------------------------
// sequential IVON delta-rule scan — R14 winner, UNCHANGED (control).
// ---------------------------------------------------------------------------
#define TC 16   // steps per LDS tile

__global__ __launch_bounds__(256) void scan_kernel(
    const float* __restrict__ qc, const float* __restrict__ kc,
    const float* __restrict__ vc, const float* __restrict__ beta,
    float* __restrict__ o) {
  __shared__ float4 ks[2][TC][16];
  __shared__ float4 qs[2][TC][16];
  __shared__ float2 vb[2][TC][16];

  const int tid  = threadIdx.x;
  const int lane = tid & 63;
  const int w    = tid >> 6;
  const int g    = lane & 15;
  const int cgrp = lane >> 4;
  const int bid  = blockIdx.x;
  const int vq   = bid >> 4;
  const int bh   = bid & 15;
  const int b = bh >> 3, h = bh & 7;
  const int colbase = vq * 16;
  const int cc = w * 4 + cgrp;
  const int v  = colbase + cc;

  const size_t base2 = ((size_t)b * Tt) * HK + h * 64;
  const float* bp = beta + ((size_t)b * Tt) * Hh + h;
  float* op = o + base2 + v;

  const int sr = tid >> 4;
  const int sg = tid & 15;

  {
    float4 k4 = *(const float4*)(kc + base2 + (size_t)sr * HK + sg * 4);
    float4 q4 = *(const float4*)(qc + base2 + (size_t)sr * HK + sg * 4);
    float  vv = vc[base2 + (size_t)sr * HK + colbase + sg];
    float  lb = (0.1f * LRc) * bp[(size_t)sr * Hh];
    ks[0][sr][sg] = k4;
    qs[0][sr][sg] = q4;
    vb[0][sr][sg] = make_float2(vv, lb);
    __syncthreads();
  }

  float S0 = 0, S1 = 0, S2 = 0, S3 = 0;
  float G0 = 0, G1 = 0, G2 = 0, G3 = 0;
  float H0 = 0, H1 = 0, H2 = 0, H3 = 0;
  float r0 = 1.f, r1 = 1.f, r2 = 1.f, r3 = 1.f;

  for (int tile = 0; tile < Tt / TC; ++tile) {
    const int d = tile & 1;
    const int t0 = tile * TC;
    const int more = (tile + 1 < Tt / TC);
    const int tn = more ? t0 + TC : t0;

    float4 nk = *(const float4*)(kc + base2 + (size_t)(tn + sr) * HK + sg * 4);
    float4 nq = *(const float4*)(qc + base2 + (size_t)(tn + sr) * HK + sg * 4);
    float  nv = vc[base2 + (size_t)(tn + sr) * HK + colbase + sg];
    float  nb = (0.1f * LRc) * bp[(size_t)(tn + sr) * Hh];

    float4 kcur = ks[d][0][g];
    float4 qcur = qs[d][0][g];
    float2 vbc  = vb[d][0][cc];
#pragma unroll
    for (int s = 0; s < TC; ++s) {
      float4 knx, qnx; float2 vbn;
      if (s + 1 < TC) {
        knx = ks[d][s + 1][g];
        qnx = qs[d][s + 1][g];
        vbn = vb[d][s + 1][cc];
      }
      const float vv = vbc.x, lrb = vbc.y;

      const float pp = fmaf(kcur.x, S0,
                       fmaf(kcur.y, S1,
                       fmaf(kcur.z, S2, kcur.w * S3)));
      const float pred = reduce16(pp);
      const float diff = pred - vv;

      const float gr0 = kcur.x * diff;
      const float gr1 = kcur.y * diff;
      const float gr2 = kcur.z * diff;
      const float gr3 = kcur.w * diff;
      G0 = fmaf(B1c, G0, gr0);
      G1 = fmaf(B1c, G1, gr1);
      G2 = fmaf(B1c, G2, gr2);
      G3 = fmaf(B1c, G3, gr3);
      H0 = fmaf(B2c, H0, gr0 * gr0);
      H1 = fmaf(B2c, H1, gr1 * gr1);
      H2 = fmaf(B2c, H2, gr2 * gr2);
      H3 = fmaf(B2c, H3, gr3 * gr3);
      const float d0 = fmaf(H0, 0.001f, 1.0f);
      const float d1 = fmaf(H1, 0.001f, 1.0f);
      const float d2 = fmaf(H2, 0.001f, 1.0f);
      const float d3 = fmaf(H3, 0.001f, 1.0f);
      r0 = r0 * fmaf(-d0, r0, 2.0f);
      r1 = r1 * fmaf(-d1, r1, 2.0f);
      r2 = r2 * fmaf(-d2, r2, 2.0f);
      r3 = r3 * fmaf(-d3, r3, 2.0f);
      S0 = fmaf(-lrb, G0 * r0, S0);
      S1 = fmaf(-lrb, G1 * r1, S1);
      S2 = fmaf(-lrb, G2 * r2, S2);
      S3 = fmaf(-lrb, G3 * r3, S3);

      const float po = fmaf(qcur.x, S0,
                       fmaf(qcur.y, S1,
                       fmaf(qcur.z, S2, qcur.w * S3)));
      const float ro = reduce16(po);
      op[(size_t)(t0 + s) * HK] = ro;
      if (s + 1 < TC) { kcur = knx; qcur = qnx; vbc = vbn; }
    }

    if (more) {
      ks[d ^ 1][sr][sg] = nk;
      qs[d ^ 1][sr][sg] = nq;
      vb[d ^ 1][sr][sg] = make_float2(nv, nb);
    }
    __syncthreads();
  }
}

// ---------------------------------------------------------------------------
// RMSNorm over V=64, writes bf16 hi/lo for the MFMA output projection
// ---------------------------------------------------------------------------
__global__ __launch_bounds__(256) void rmsnorm_kernel(
    const float* __restrict__ o, const float* __restrict__ rmsw,
    unsigned short* __restrict__ hi, unsigned short* __restrict__ lo) {
  const int idx = blockIdx.x * 4 + (threadIdx.x >> 6);
  const int lane = threadIdx.x & 63;
  const float* p = o + (size_t)idx * 64;
  float y = p[lane];
  float ss = reduce64(y * y);
  y = y * rsqrtf(ss * (1.f / 64.f) + 1e-5f) * rmsw[lane];
  unsigned short h = f2bf(y);
  hi[(size_t)idx * 64 + lane] = h;
  lo[(size_t)idx * 64 + lane] = f2bf(y - bf2f(h));
}

// ---------------------------------------------------------------------------
extern "C" void kernel_launch(void* const* d_in, const int* in_sizes, int n_in,
                              void* d_out, int out_size, void* d_ws, size_t ws_size,
                              hipStream_t stream) {
  const float* x    = (const float*)d_in[0];
  const float* Wq   = (const float*)d_in[1];
  const float* Wk   = (const float*)d_in[2];
  const float* Wv   = (const float*)d_in[3];
  const float* Wb   = (const float*)d_in[4];
  const float* cwq  = (const float*)d_in[5];
  const float* cwk  = (const float*)d_in[6];
  const float* cwv  = (const float*)d_in[7];
  const float* rmsw = (const float*)d_in[8];
  const float* Wo   = (const float*)d_in[9];
  float* out = (float*)d_out;
  float* ws  = (float*)d_ws;

  const size_t SZ = (size_t)BT * HK;   // 1,048,576 floats
  float* qp   = ws;            // pre-conv q / scan output `on`
  float* kp   = ws + 1 * SZ;   // pre-conv k; dead after conv -> onhi
  float* vp   = ws + 2 * SZ;   // pre-conv v; dead after conv -> onlo
  float* qc   = ws + 3 * SZ;   // conv q; slot hosts xhi/xlo BEFORE conv
  float* kc   = ws + 4 * SZ;   // conv k; slot hosts Wqkv hi/lo BEFORE conv
  float* vc   = ws + 5 * SZ;   // conv v; slot hosts Wo hi/lo AFTER scan
  float* beta = ws + 6 * SZ;   // 16384 floats
  float* on   = qp;

  // phase-overlapped bf16 buffers (no extra workspace):
  unsigned short* xhi  = (unsigned short*)qc;                 // SZ ushorts
  unsigned short* xlo  = xhi + SZ;
  unsigned short* wh3  = (unsigned short*)kc;                 // 3*256K ushorts
  unsigned short* wl3  = wh3 + 3 * 512 * 512;
  unsigned short* wohi = (unsigned short*)vc;                 // 256K ushorts
  unsigned short* wolo = wohi + 512 * 512;
  unsigned short* onhi = (unsigned short*)kp;
  unsigned short* onlo = (unsigned short*)vp;

  // 1. convert x and Wq/Wk/Wv to split-bf16 (W transposed to [n][k])
  cvt_x_kernel<<<dim3(BT * Dd / (256 * 8)), 256, 0, stream>>>(x, xhi, xlo);
  cvt_w_kernel<<<dim3(8, 8, 3), 256, 0, stream>>>(Wq, Wk, Wv, wh3, wl3);
  // 2. projections via MFMA
  gemm3_mfma_kernel<<<dim3(BT / 64, HK / 64, 3), 256, 0, stream>>>(
      xhi, xlo, wh3, wl3, qp, kp, vp);
  // 3. beta
  beta_kernel<<<dim3(BT * Hh / 256), 256, 0, stream>>>(x, Wb, beta);
  // 4. conv + silu + l2norm (overwrites xhi/wh3 slots — both dead)
  conv_kernel<<<dim3(Bb * Tt * Hh / 4, 1, 3), 256, 0, stream>>>(
      qp, kp, vp, cwq, cwk, cwv, qc, kc, vc);
  // 5. sequential scan (unchanged control)
  scan_kernel<<<dim3(Bb * Hh * (Vv / 16)), 256, 0, stream>>>(
      qc, kc, vc, beta, on);
  // 6. convert Wo into dead vc slot
  cvt_w_kernel<<<dim3(8, 8, 1), 256, 0, stream>>>(Wo, Wo, Wo, wohi, wolo);
  // 7. RMSNorm -> split-bf16 `on` (into dead kp/vp slots)
  rmsnorm_kernel<<<dim3(Bb * Tt * Hh / 4), 256, 0, stream>>>(on, rmsw, onhi, onlo);
  // 8. output projection via MFMA
  gemm1_mfma_kernel<<<dim3(BT / 64, HK / 64, 1), 256, 0, stream>>>(
      onhi, onlo, wohi, wolo, out);
}

// Round 17
// 214.860 us; speedup vs baseline: 1.6839x; 1.0238x over previous
//
#include <hip/hip_runtime.h>
#include <hip/hip_bf16.h>
#include <math.h>

// Dims (compile-time constants for this problem)
#define Bb 2
#define Tt 1024
#define Dd 512
#define Hh 8
#define Kk 64
#define Vv 64
#define BT (Bb*Tt)          // 2048
#define HK (Hh*Kk)          // 512

// hyperparams
#define B1c 0.9f
#define B2c 0.999f
#define LRc 1e-3f
#define SCALEc 0.125f       // 64^-0.5

typedef short s8v __attribute__((ext_vector_type(8)));   // 8 bf16 = 4 VGPR
typedef float f4v __attribute__((ext_vector_type(4)));   // MFMA acc

// ---------------------------------------------------------------------------
// bf16 split helpers (RNE)
// ---------------------------------------------------------------------------
__device__ __forceinline__ unsigned short f2bf(float x) {
  unsigned u = __float_as_uint(x);
  u += 0x7FFFu + ((u >> 16) & 1u);
  return (unsigned short)(u >> 16);
}
__device__ __forceinline__ float bf2f(unsigned short h) {
  return __uint_as_float((unsigned)h << 16);
}

// ---------------------------------------------------------------------------
// Cross-lane helpers: all-VALU butterfly stages
// ---------------------------------------------------------------------------
template <int CTRL>
__device__ __forceinline__ float dpp_add(float v) {
  int y = __builtin_amdgcn_update_dpp(0, __float_as_int(v), CTRL, 0xF, 0xF, true);
  return v + __int_as_float(y);
}

typedef unsigned uint2_t __attribute__((ext_vector_type(2)));

__device__ __forceinline__ float xor16_add(float x) {
#if __has_builtin(__builtin_amdgcn_permlane16_swap)
  uint2_t r = __builtin_amdgcn_permlane16_swap(__float_as_uint(x), __float_as_uint(x),
                                               false, false);
  return __uint_as_float(r.x) + __uint_as_float(r.y);
#else
  int y = __builtin_amdgcn_ds_swizzle(__float_as_int(x), 0x401F);
  return x + __int_as_float(y);
#endif
}

__device__ __forceinline__ float xor32_add(float x) {
#if __has_builtin(__builtin_amdgcn_permlane32_swap)
  uint2_t r = __builtin_amdgcn_permlane32_swap(__float_as_uint(x), __float_as_uint(x),
                                               false, false);
  return __uint_as_float(r.x) + __uint_as_float(r.y);
#else
  return x + __shfl_xor(x, 32, 64);
#endif
}

__device__ __forceinline__ float reduce16(float x) {
  x = dpp_add<0xB1>(x);
  x = dpp_add<0x4E>(x);
  x = dpp_add<0x141>(x);
  x = dpp_add<0x140>(x);
  return x;
}

__device__ __forceinline__ float reduce64(float x) {
  x = reduce16(x);
  x = xor16_add(x);
  x = xor32_add(x);
  return x;
}

// ---------------------------------------------------------------------------
// cvt_x: fp32 [M][512] -> hi/lo bf16 [M][512] (row-major)
// ---------------------------------------------------------------------------
__global__ __launch_bounds__(256) void cvt_x_kernel(
    const float* __restrict__ x, unsigned short* __restrict__ hi,
    unsigned short* __restrict__ lo) {
  const int i = (blockIdx.x * 256 + threadIdx.x) * 8;
  float4 a = *(const float4*)(x + i);
  float4 b = *(const float4*)(x + i + 4);
  const float v[8] = {a.x, a.y, a.z, a.w, b.x, b.y, b.z, b.w};
  union { unsigned short u[8]; uint4 q; } ph, pl;
#pragma unroll
  for (int j = 0; j < 8; ++j) {
    unsigned short h = f2bf(v[j]);
    ph.u[j] = h;
    pl.u[j] = f2bf(v[j] - bf2f(h));
  }
  *(uint4*)(hi + i) = ph.q;
  *(uint4*)(lo + i) = pl.q;
}

// ---------------------------------------------------------------------------
// cvt_w: W [512 k][512 n] fp32 -> hi/lo bf16 TRANSPOSED [n][k].
// ---------------------------------------------------------------------------
__global__ __launch_bounds__(256) void cvt_w_kernel(
    const float* __restrict__ W0, const float* __restrict__ W1,
    const float* __restrict__ W2,
    unsigned short* __restrict__ hib, unsigned short* __restrict__ lob) {
  __shared__ float Ts[64][65];
  const int z = blockIdx.z;
  const float* W = (z == 0) ? W0 : (z == 1) ? W1 : W2;
  unsigned short* hi = hib + (size_t)z * 512 * 512;
  unsigned short* lo = lob + (size_t)z * 512 * 512;
  const int tk = blockIdx.x * 64;
  const int tn = blockIdx.y * 64;
  const int r  = threadIdx.x >> 2;
  const int cg = threadIdx.x & 3;
#pragma unroll
  for (int j = 0; j < 4; ++j) {
    float4 v = *(const float4*)(W + (size_t)(tk + r) * 512 + tn + cg * 16 + j * 4);
    Ts[r][cg * 16 + j * 4 + 0] = v.x;
    Ts[r][cg * 16 + j * 4 + 1] = v.y;
    Ts[r][cg * 16 + j * 4 + 2] = v.z;
    Ts[r][cg * 16 + j * 4 + 3] = v.w;
  }
  __syncthreads();
  union { unsigned short u[16]; uint4 q[2]; } ph, pl;
#pragma unroll
  for (int j = 0; j < 16; ++j) {
    float v = Ts[cg * 16 + j][r];
    unsigned short h = f2bf(v);
    ph.u[j] = h;
    pl.u[j] = f2bf(v - bf2f(h));
  }
  const size_t ob = (size_t)(tn + r) * 512 + tk + cg * 16;
  *(uint4*)(hi + ob) = ph.q[0];
  *(uint4*)(hi + ob + 8) = ph.q[1];
  *(uint4*)(lo + ob) = pl.q[0];
  *(uint4*)(lo + ob + 8) = pl.q[1];
}

// ---------------------------------------------------------------------------
// split-bf16 MFMA GEMM (R16 winner, unchanged)
// ---------------------------------------------------------------------------
__device__ __forceinline__ void gemm_mfma_body(
    const unsigned short* __restrict__ Ahi, const unsigned short* __restrict__ Alo,
    const unsigned short* __restrict__ Bhi, const unsigned short* __restrict__ Blo,
    float* __restrict__ C) {
  __shared__ unsigned short Ah[64][40], Al[64][40], Bh[64][40], Bl[64][40];
  const int tid = threadIdx.x;
  const int bm = blockIdx.x * 64;
  const int bn = blockIdx.y * 64;
  const int srow = tid >> 2;
  const int skoff = (tid & 3) * 8;
  const int l = tid & 63, w = tid >> 6;
  const int arow = (l & 15) + 16 * w;
  const int koff = (l >> 4) * 8;

  const unsigned short* pAh = Ahi + (size_t)(bm + srow) * 512 + skoff;
  const unsigned short* pAl = Alo + (size_t)(bm + srow) * 512 + skoff;
  const unsigned short* pBh = Bhi + (size_t)(bn + srow) * 512 + skoff;
  const unsigned short* pBl = Blo + (size_t)(bn + srow) * 512 + skoff;

  f4v acc0 = {0.f, 0.f, 0.f, 0.f}, acc1 = acc0, acc2 = acc0, acc3 = acc0;

  uint4 rah = *(const uint4*)(pAh);
  uint4 ral = *(const uint4*)(pAl);
  uint4 rbh = *(const uint4*)(pBh);
  uint4 rbl = *(const uint4*)(pBl);

  for (int k0 = 0; k0 < 512; k0 += 32) {
    __syncthreads();
    *(uint4*)&Ah[srow][skoff] = rah;
    *(uint4*)&Al[srow][skoff] = ral;
    *(uint4*)&Bh[srow][skoff] = rbh;
    *(uint4*)&Bl[srow][skoff] = rbl;
    __syncthreads();
    if (k0 + 32 < 512) {
      rah = *(const uint4*)(pAh + k0 + 32);
      ral = *(const uint4*)(pAl + k0 + 32);
      rbh = *(const uint4*)(pBh + k0 + 32);
      rbl = *(const uint4*)(pBl + k0 + 32);
    }
    const s8v ah = *(const s8v*)&Ah[arow][koff];
    const s8v al = *(const s8v*)&Al[arow][koff];
#pragma unroll
    for (int c = 0; c < 4; ++c) {
      const s8v bh = *(const s8v*)&Bh[16 * c + (l & 15)][koff];
      const s8v bl = *(const s8v*)&Bl[16 * c + (l & 15)][koff];
      f4v* acc = (c == 0) ? &acc0 : (c == 1) ? &acc1 : (c == 2) ? &acc2 : &acc3;
      *acc = __builtin_amdgcn_mfma_f32_16x16x32_bf16(al, bh, *acc, 0, 0, 0);
      *acc = __builtin_amdgcn_mfma_f32_16x16x32_bf16(ah, bl, *acc, 0, 0, 0);
      *acc = __builtin_amdgcn_mfma_f32_16x16x32_bf16(ah, bh, *acc, 0, 0, 0);
    }
  }

  const int crow = bm + 16 * w + (l >> 4) * 4;
  const int ccol = bn + (l & 15);
#pragma unroll
  for (int i = 0; i < 4; ++i) {
    C[(size_t)(crow + i) * 512 + ccol + 0]  = acc0[i];
    C[(size_t)(crow + i) * 512 + ccol + 16] = acc1[i];
    C[(size_t)(crow + i) * 512 + ccol + 32] = acc2[i];
    C[(size_t)(crow + i) * 512 + ccol + 48] = acc3[i];
  }
}

__global__ __launch_bounds__(256) void gemm3_mfma_kernel(
    const unsigned short* __restrict__ xhi, const unsigned short* __restrict__ xlo,
    const unsigned short* __restrict__ whi, const unsigned short* __restrict__ wlo,
    float* __restrict__ qp, float* __restrict__ kp, float* __restrict__ vp) {
  const int z = blockIdx.z;
  float* Cp = (z == 0) ? qp : (z == 1) ? kp : vp;
  gemm_mfma_body(xhi, xlo, whi + (size_t)z * 512 * 512, wlo + (size_t)z * 512 * 512, Cp);
}

__global__ __launch_bounds__(256) void gemm1_mfma_kernel(
    const unsigned short* __restrict__ ahi, const unsigned short* __restrict__ alo,
    const unsigned short* __restrict__ whi, const unsigned short* __restrict__ wlo,
    float* __restrict__ C) {
  gemm_mfma_body(ahi, alo, whi, wlo, C);
}

// ---------------------------------------------------------------------------
// beta = sigmoid(x @ Wb) (float4-vectorized)
// ---------------------------------------------------------------------------
__global__ __launch_bounds__(256) void beta_kernel(const float* __restrict__ x,
                                                   const float* __restrict__ Wb,
                                                   float* __restrict__ beta) {
  int gid = blockIdx.x * blockDim.x + threadIdx.x;
  int bt = gid >> 3, h = gid & 7;
  const float4* xr = (const float4*)(x + (size_t)bt * Dd);
  float s = 0.f;
#pragma unroll 4
  for (int d4 = 0; d4 < Dd / 4; ++d4) {
    float4 xv = xr[d4];
    const float* wb = Wb + (d4 * 4) * Hh + h;
    s = fmaf(xv.x, wb[0 * Hh], s);
    s = fmaf(xv.y, wb[1 * Hh], s);
    s = fmaf(xv.z, wb[2 * Hh], s);
    s = fmaf(xv.w, wb[3 * Hh], s);
  }
  beta[gid] = 1.f / (1.f + expf(-s));
}

// ---------------------------------------------------------------------------
// causal depthwise conv(4) + SiLU (+ optional L2 norm + scale)
// ---------------------------------------------------------------------------
__global__ __launch_bounds__(256) void conv_kernel(
    const float* __restrict__ qp, const float* __restrict__ kp,
    const float* __restrict__ vp,
    const float* __restrict__ cwq, const float* __restrict__ cwk,
    const float* __restrict__ cwv,
    float* __restrict__ qc, float* __restrict__ kc, float* __restrict__ vc) {
  const int mode = blockIdx.z;
  const float* pre; const float* cw; float* post;
  if (mode == 0)      { pre = qp; cw = cwq; post = qc; }
  else if (mode == 1) { pre = kp; cw = cwk; post = kc; }
  else                { pre = vp; cw = cwv; post = vc; }

  const int idx = blockIdx.x * 4 + (threadIdx.x >> 6);
  const int lane = threadIdx.x & 63;
  const int b = idx >> 13;
  const int th = idx & 8191;
  const int t = th >> 3;
  const int h = th & 7;
  const int ch = h * 64 + lane;

  float y = 0.f;
#pragma unroll
  for (int i = 0; i < 4; ++i) {
    int tt = t + i - 3;
    if (tt >= 0)
      y += pre[((size_t)(b * Tt + tt)) * HK + ch] * cw[ch * 4 + i];
  }
  y = y / (1.f + expf(-y));
  if (mode < 2) {
    float ss = reduce64(y * y);
    y *= rsqrtf(ss + 1e-6f);
    if (mode == 0) y *= SCALEc;
  }
  post[((size_t)(b * Tt + t)) * HK + ch] = y;
}

// ---------------------------------------------------------------------------
// sequential IVON delta-rule scan — R14 staging, interleaved tail reduces.
//
// R13's interleave retried WITHOUT its staging confound (write-first + 2nd
// barrier). pred_{s+1} = reduce(k_{s+1}.S_{s+1}) is computed in step s's
// tail, its 4 DPP stages interleaved op-by-op with the o-reduce's 4 stages
// (independent chains share stall windows: ~152 -> ~90cy). k_{s+1} is in the
// CURRENT buffer for s<15; the tile boundary is handled by one standalone
// reduce at the next tile's top (stalls overlap next-tile load issue).
// ---------------------------------------------------------------------------
#define TC 16   // steps per LDS tile

__global__ __launch_bounds__(256) void scan_kernel(
    const float* __restrict__ qc, const float* __restrict__ kc,
    const float* __restrict__ vc, const float* __restrict__ beta,
    float* __restrict__ o) {
  __shared__ float4 ks[2][TC][16];
  __shared__ float4 qs[2][TC][16];
  __shared__ float2 vb[2][TC][16];

  const int tid  = threadIdx.x;
  const int lane = tid & 63;
  const int w    = tid >> 6;
  const int g    = lane & 15;
  const int cgrp = lane >> 4;
  const int bid  = blockIdx.x;
  const int vq   = bid >> 4;
  const int bh   = bid & 15;
  const int b = bh >> 3, h = bh & 7;
  const int colbase = vq * 16;
  const int cc = w * 4 + cgrp;
  const int v  = colbase + cc;

  const size_t base2 = ((size_t)b * Tt) * HK + h * 64;
  const float* bp = beta + ((size_t)b * Tt) * Hh + h;
  float* op = o + base2 + v;

  const int sr = tid >> 4;
  const int sg = tid & 15;

  {
    float4 k4 = *(const float4*)(kc + base2 + (size_t)sr * HK + sg * 4);
    float4 q4 = *(const float4*)(qc + base2 + (size_t)sr * HK + sg * 4);
    float  vv = vc[base2 + (size_t)sr * HK + colbase + sg];
    float  lb = (0.1f * LRc) * bp[(size_t)sr * Hh];
    ks[0][sr][sg] = k4;
    qs[0][sr][sg] = q4;
    vb[0][sr][sg] = make_float2(vv, lb);
    __syncthreads();
  }

  float S0 = 0, S1 = 0, S2 = 0, S3 = 0;
  float G0 = 0, G1 = 0, G2 = 0, G3 = 0;
  float H0 = 0, H1 = 0, H2 = 0, H3 = 0;
  float r0 = 1.f, r1 = 1.f, r2 = 1.f, r3 = 1.f;

  for (int tile = 0; tile < Tt / TC; ++tile) {
    const int d = tile & 1;
    const int t0 = tile * TC;
    const int more = (tile + 1 < Tt / TC);
    const int tn = more ? t0 + TC : t0;

    // issue next tile's global loads (completion hidden under compute)
    float4 nk = *(const float4*)(kc + base2 + (size_t)(tn + sr) * HK + sg * 4);
    float4 nq = *(const float4*)(qc + base2 + (size_t)(tn + sr) * HK + sg * 4);
    float  nv = vc[base2 + (size_t)(tn + sr) * HK + colbase + sg];
    float  nb = (0.1f * LRc) * bp[(size_t)(tn + sr) * Hh];

    // tile-top pred for step 0 (stalls overlap the load issue above);
    // tile 0: S=0 -> pred=0 naturally.
    float4 kt = ks[d][0][g];
    float pred = reduce16(fmaf(kt.x, S0,
                          fmaf(kt.y, S1,
                          fmaf(kt.z, S2, kt.w * S3))));

#pragma unroll
    for (int s = 0; s < TC; ++s) {
      const float4 kv = ks[d][s][g];
      const float4 qv = qs[d][s][g];
      const float2 vbc = vb[d][s][cc];
      const float vv = vbc.x, lrb = vbc.y;

      const float diff = pred - vv;
      const float gr0 = kv.x * diff;
      const float gr1 = kv.y * diff;
      const float gr2 = kv.z * diff;
      const float gr3 = kv.w * diff;
      G0 = fmaf(B1c, G0, gr0);
      G1 = fmaf(B1c, G1, gr1);
      G2 = fmaf(B1c, G2, gr2);
      G3 = fmaf(B1c, G3, gr3);
      H0 = fmaf(B2c, H0, gr0 * gr0);
      H1 = fmaf(B2c, H1, gr1 * gr1);
      H2 = fmaf(B2c, H2, gr2 * gr2);
      H3 = fmaf(B2c, H3, gr3 * gr3);
      const float d0 = fmaf(H0, 0.001f, 1.0f);
      const float d1 = fmaf(H1, 0.001f, 1.0f);
      const float d2 = fmaf(H2, 0.001f, 1.0f);
      const float d3 = fmaf(H3, 0.001f, 1.0f);
      r0 = r0 * fmaf(-d0, r0, 2.0f);
      r1 = r1 * fmaf(-d1, r1, 2.0f);
      r2 = r2 * fmaf(-d2, r2, 2.0f);
      r3 = r3 * fmaf(-d3, r3, 2.0f);
      S0 = fmaf(-lrb, G0 * r0, S0);
      S1 = fmaf(-lrb, G1 * r1, S1);
      S2 = fmaf(-lrb, G2 * r2, S2);
      S3 = fmaf(-lrb, G3 * r3, S3);

      float po = fmaf(qv.x, S0,
                 fmaf(qv.y, S1,
                 fmaf(qv.z, S2, qv.w * S3)));
      if (s + 1 < TC) {
        const float4 k1 = ks[d][s + 1][g];
        float pp = fmaf(k1.x, S0,
                   fmaf(k1.y, S1,
                   fmaf(k1.z, S2, k1.w * S3)));
        // interleave the two independent 4-stage chains
        po = dpp_add<0xB1>(po);   pp = dpp_add<0xB1>(pp);
        po = dpp_add<0x4E>(po);   pp = dpp_add<0x4E>(pp);
        po = dpp_add<0x141>(po);  pp = dpp_add<0x141>(pp);
        po = dpp_add<0x140>(po);  pp = dpp_add<0x140>(pp);
        pred = pp;
      } else {
        po = reduce16(po);
      }
      op[(size_t)(t0 + s) * HK] = po;   // maskless: uniform per 16-group
    }

    // write next tile into the other buffer; single barrier per tile
    if (more) {
      ks[d ^ 1][sr][sg] = nk;
      qs[d ^ 1][sr][sg] = nq;
      vb[d ^ 1][sr][sg] = make_float2(nv, nb);
    }
    __syncthreads();
  }
}

// ---------------------------------------------------------------------------
// RMSNorm over V=64, writes bf16 hi/lo for the MFMA output projection
// ---------------------------------------------------------------------------
__global__ __launch_bounds__(256) void rmsnorm_kernel(
    const float* __restrict__ o, const float* __restrict__ rmsw,
    unsigned short* __restrict__ hi, unsigned short* __restrict__ lo) {
  const int idx = blockIdx.x * 4 + (threadIdx.x >> 6);
  const int lane = threadIdx.x & 63;
  const float* p = o + (size_t)idx * 64;
  float y = p[lane];
  float ss = reduce64(y * y);
  y = y * rsqrtf(ss * (1.f / 64.f) + 1e-5f) * rmsw[lane];
  unsigned short h = f2bf(y);
  hi[(size_t)idx * 64 + lane] = h;
  lo[(size_t)idx * 64 + lane] = f2bf(y - bf2f(h));
}

// ---------------------------------------------------------------------------
extern "C" void kernel_launch(void* const* d_in, const int* in_sizes, int n_in,
                              void* d_out, int out_size, void* d_ws, size_t ws_size,
                              hipStream_t stream) {
  const float* x    = (const float*)d_in[0];
  const float* Wq   = (const float*)d_in[1];
  const float* Wk   = (const float*)d_in[2];
  const float* Wv   = (const float*)d_in[3];
  const float* Wb   = (const float*)d_in[4];
  const float* cwq  = (const float*)d_in[5];
  const float* cwk  = (const float*)d_in[6];
  const float* cwv  = (const float*)d_in[7];
  const float* rmsw = (const float*)d_in[8];
  const float* Wo   = (const float*)d_in[9];
  float* out = (float*)d_out;
  float* ws  = (float*)d_ws;

  const size_t SZ = (size_t)BT * HK;   // 1,048,576 floats
  float* qp   = ws;            // pre-conv q / scan output `on`
  float* kp   = ws + 1 * SZ;   // pre-conv k; dead after conv -> onhi
  float* vp   = ws + 2 * SZ;   // pre-conv v; dead after conv -> onlo
  float* qc   = ws + 3 * SZ;   // conv q; hosts xhi/xlo BEFORE conv
  float* kc   = ws + 4 * SZ;   // conv k; hosts Wqkv hi/lo BEFORE conv
  float* vc   = ws + 5 * SZ;   // conv v; hosts Wo hi/lo AFTER scan
  float* beta = ws + 6 * SZ;   // 16384 floats
  float* on   = qp;

  unsigned short* xhi  = (unsigned short*)qc;
  unsigned short* xlo  = xhi + SZ;
  unsigned short* wh3  = (unsigned short*)kc;
  unsigned short* wl3  = wh3 + 3 * 512 * 512;
  unsigned short* wohi = (unsigned short*)vc;
  unsigned short* wolo = wohi + 512 * 512;
  unsigned short* onhi = (unsigned short*)kp;
  unsigned short* onlo = (unsigned short*)vp;

  // 1. convert x and Wq/Wk/Wv to split-bf16 (W transposed to [n][k])
  cvt_x_kernel<<<dim3(BT * Dd / (256 * 8)), 256, 0, stream>>>(x, xhi, xlo);
  cvt_w_kernel<<<dim3(8, 8, 3), 256, 0, stream>>>(Wq, Wk, Wv, wh3, wl3);
  // 2. projections via MFMA
  gemm3_mfma_kernel<<<dim3(BT / 64, HK / 64, 3), 256, 0, stream>>>(
      xhi, xlo, wh3, wl3, qp, kp, vp);
  // 3. beta
  beta_kernel<<<dim3(BT * Hh / 256), 256, 0, stream>>>(x, Wb, beta);
  // 4. conv + silu + l2norm
  conv_kernel<<<dim3(Bb * Tt * Hh / 4, 1, 3), 256, 0, stream>>>(
      qp, kp, vp, cwq, cwk, cwv, qc, kc, vc);
  // 5. sequential scan (interleaved tail reduces)
  scan_kernel<<<dim3(Bb * Hh * (Vv / 16)), 256, 0, stream>>>(
      qc, kc, vc, beta, on);
  // 6. convert Wo into dead vc slot
  cvt_w_kernel<<<dim3(8, 8, 1), 256, 0, stream>>>(Wo, Wo, Wo, wohi, wolo);
  // 7. RMSNorm -> split-bf16 `on`
  rmsnorm_kernel<<<dim3(Bb * Tt * Hh / 4), 256, 0, stream>>>(on, rmsw, onhi, onlo);
  // 8. output projection via MFMA
  gemm1_mfma_kernel<<<dim3(BT / 64, HK / 64, 1), 256, 0, stream>>>(
      onhi, onlo, wohi, wolo, out);
}

// Round 18
// 208.058 us; speedup vs baseline: 1.7389x; 1.0327x over previous
//
#include <hip/hip_runtime.h>
#include <hip/hip_bf16.h>
#include <math.h>

// Dims (compile-time constants for this problem)
#define Bb 2
#define Tt 1024
#define Dd 512
#define Hh 8
#define Kk 64
#define Vv 64
#define BT (Bb*Tt)          // 2048
#define HK (Hh*Kk)          // 512

// hyperparams
#define B1c 0.9f
#define B2c 0.999f
#define LRc 1e-3f
#define SCALEc 0.125f       // 64^-0.5

typedef short s8v __attribute__((ext_vector_type(8)));   // 8 bf16 = 4 VGPR
typedef float f4v __attribute__((ext_vector_type(4)));   // MFMA acc

// ---------------------------------------------------------------------------
// bf16 split helpers (RNE)
// ---------------------------------------------------------------------------
__device__ __forceinline__ unsigned short f2bf(float x) {
  unsigned u = __float_as_uint(x);
  u += 0x7FFFu + ((u >> 16) & 1u);
  return (unsigned short)(u >> 16);
}
__device__ __forceinline__ float bf2f(unsigned short h) {
  return __uint_as_float((unsigned)h << 16);
}

// ---------------------------------------------------------------------------
// Cross-lane helpers: all-VALU butterfly stages
// ---------------------------------------------------------------------------
template <int CTRL>
__device__ __forceinline__ float dpp_add(float v) {
  int y = __builtin_amdgcn_update_dpp(0, __float_as_int(v), CTRL, 0xF, 0xF, true);
  return v + __int_as_float(y);
}

typedef unsigned uint2_t __attribute__((ext_vector_type(2)));

__device__ __forceinline__ float xor16_add(float x) {
#if __has_builtin(__builtin_amdgcn_permlane16_swap)
  uint2_t r = __builtin_amdgcn_permlane16_swap(__float_as_uint(x), __float_as_uint(x),
                                               false, false);
  return __uint_as_float(r.x) + __uint_as_float(r.y);
#else
  int y = __builtin_amdgcn_ds_swizzle(__float_as_int(x), 0x401F);
  return x + __int_as_float(y);
#endif
}

__device__ __forceinline__ float xor32_add(float x) {
#if __has_builtin(__builtin_amdgcn_permlane32_swap)
  uint2_t r = __builtin_amdgcn_permlane32_swap(__float_as_uint(x), __float_as_uint(x),
                                               false, false);
  return __uint_as_float(r.x) + __uint_as_float(r.y);
#else
  return x + __shfl_xor(x, 32, 64);
#endif
}

__device__ __forceinline__ float reduce16(float x) {
  x = dpp_add<0xB1>(x);
  x = dpp_add<0x4E>(x);
  x = dpp_add<0x141>(x);
  x = dpp_add<0x140>(x);
  return x;
}

__device__ __forceinline__ float reduce64(float x) {
  x = reduce16(x);
  x = xor16_add(x);
  x = xor32_add(x);
  return x;
}

// ---------------------------------------------------------------------------
// cvt_x: fp32 [M][512] -> hi/lo bf16 [M][512] (row-major)
// ---------------------------------------------------------------------------
__global__ __launch_bounds__(256) void cvt_x_kernel(
    const float* __restrict__ x, unsigned short* __restrict__ hi,
    unsigned short* __restrict__ lo) {
  const int i = (blockIdx.x * 256 + threadIdx.x) * 8;
  float4 a = *(const float4*)(x + i);
  float4 b = *(const float4*)(x + i + 4);
  const float v[8] = {a.x, a.y, a.z, a.w, b.x, b.y, b.z, b.w};
  union { unsigned short u[8]; uint4 q; } ph, pl;
#pragma unroll
  for (int j = 0; j < 8; ++j) {
    unsigned short h = f2bf(v[j]);
    ph.u[j] = h;
    pl.u[j] = f2bf(v[j] - bf2f(h));
  }
  *(uint4*)(hi + i) = ph.q;
  *(uint4*)(lo + i) = pl.q;
}

// ---------------------------------------------------------------------------
// cvt_w: W [512 k][512 n] fp32 -> hi/lo bf16 TRANSPOSED [n][k].
// ---------------------------------------------------------------------------
__global__ __launch_bounds__(256) void cvt_w_kernel(
    const float* __restrict__ W0, const float* __restrict__ W1,
    const float* __restrict__ W2,
    unsigned short* __restrict__ hib, unsigned short* __restrict__ lob) {
  __shared__ float Ts[64][65];
  const int z = blockIdx.z;
  const float* W = (z == 0) ? W0 : (z == 1) ? W1 : W2;
  unsigned short* hi = hib + (size_t)z * 512 * 512;
  unsigned short* lo = lob + (size_t)z * 512 * 512;
  const int tk = blockIdx.x * 64;
  const int tn = blockIdx.y * 64;
  const int r  = threadIdx.x >> 2;
  const int cg = threadIdx.x & 3;
#pragma unroll
  for (int j = 0; j < 4; ++j) {
    float4 v = *(const float4*)(W + (size_t)(tk + r) * 512 + tn + cg * 16 + j * 4);
    Ts[r][cg * 16 + j * 4 + 0] = v.x;
    Ts[r][cg * 16 + j * 4 + 1] = v.y;
    Ts[r][cg * 16 + j * 4 + 2] = v.z;
    Ts[r][cg * 16 + j * 4 + 3] = v.w;
  }
  __syncthreads();
  union { unsigned short u[16]; uint4 q[2]; } ph, pl;
#pragma unroll
  for (int j = 0; j < 16; ++j) {
    float v = Ts[cg * 16 + j][r];
    unsigned short h = f2bf(v);
    ph.u[j] = h;
    pl.u[j] = f2bf(v - bf2f(h));
  }
  const size_t ob = (size_t)(tn + r) * 512 + tk + cg * 16;
  *(uint4*)(hi + ob) = ph.q[0];
  *(uint4*)(hi + ob + 8) = ph.q[1];
  *(uint4*)(lo + ob) = pl.q[0];
  *(uint4*)(lo + ob + 8) = pl.q[1];
}

// ---------------------------------------------------------------------------
// split-bf16 MFMA GEMM (R16 winner, unchanged)
// ---------------------------------------------------------------------------
__device__ __forceinline__ void gemm_mfma_body(
    const unsigned short* __restrict__ Ahi, const unsigned short* __restrict__ Alo,
    const unsigned short* __restrict__ Bhi, const unsigned short* __restrict__ Blo,
    float* __restrict__ C) {
  __shared__ unsigned short Ah[64][40], Al[64][40], Bh[64][40], Bl[64][40];
  const int tid = threadIdx.x;
  const int bm = blockIdx.x * 64;
  const int bn = blockIdx.y * 64;
  const int srow = tid >> 2;
  const int skoff = (tid & 3) * 8;
  const int l = tid & 63, w = tid >> 6;
  const int arow = (l & 15) + 16 * w;
  const int koff = (l >> 4) * 8;

  const unsigned short* pAh = Ahi + (size_t)(bm + srow) * 512 + skoff;
  const unsigned short* pAl = Alo + (size_t)(bm + srow) * 512 + skoff;
  const unsigned short* pBh = Bhi + (size_t)(bn + srow) * 512 + skoff;
  const unsigned short* pBl = Blo + (size_t)(bn + srow) * 512 + skoff;

  f4v acc0 = {0.f, 0.f, 0.f, 0.f}, acc1 = acc0, acc2 = acc0, acc3 = acc0;

  uint4 rah = *(const uint4*)(pAh);
  uint4 ral = *(const uint4*)(pAl);
  uint4 rbh = *(const uint4*)(pBh);
  uint4 rbl = *(const uint4*)(pBl);

  for (int k0 = 0; k0 < 512; k0 += 32) {
    __syncthreads();
    *(uint4*)&Ah[srow][skoff] = rah;
    *(uint4*)&Al[srow][skoff] = ral;
    *(uint4*)&Bh[srow][skoff] = rbh;
    *(uint4*)&Bl[srow][skoff] = rbl;
    __syncthreads();
    if (k0 + 32 < 512) {
      rah = *(const uint4*)(pAh + k0 + 32);
      ral = *(const uint4*)(pAl + k0 + 32);
      rbh = *(const uint4*)(pBh + k0 + 32);
      rbl = *(const uint4*)(pBl + k0 + 32);
    }
    const s8v ah = *(const s8v*)&Ah[arow][koff];
    const s8v al = *(const s8v*)&Al[arow][koff];
#pragma unroll
    for (int c = 0; c < 4; ++c) {
      const s8v bh = *(const s8v*)&Bh[16 * c + (l & 15)][koff];
      const s8v bl = *(const s8v*)&Bl[16 * c + (l & 15)][koff];
      f4v* acc = (c == 0) ? &acc0 : (c == 1) ? &acc1 : (c == 2) ? &acc2 : &acc3;
      *acc = __builtin_amdgcn_mfma_f32_16x16x32_bf16(al, bh, *acc, 0, 0, 0);
      *acc = __builtin_amdgcn_mfma_f32_16x16x32_bf16(ah, bl, *acc, 0, 0, 0);
      *acc = __builtin_amdgcn_mfma_f32_16x16x32_bf16(ah, bh, *acc, 0, 0, 0);
    }
  }

  const int crow = bm + 16 * w + (l >> 4) * 4;
  const int ccol = bn + (l & 15);
#pragma unroll
  for (int i = 0; i < 4; ++i) {
    C[(size_t)(crow + i) * 512 + ccol + 0]  = acc0[i];
    C[(size_t)(crow + i) * 512 + ccol + 16] = acc1[i];
    C[(size_t)(crow + i) * 512 + ccol + 32] = acc2[i];
    C[(size_t)(crow + i) * 512 + ccol + 48] = acc3[i];
  }
}

__global__ __launch_bounds__(256) void gemm3_mfma_kernel(
    const unsigned short* __restrict__ xhi, const unsigned short* __restrict__ xlo,
    const unsigned short* __restrict__ whi, const unsigned short* __restrict__ wlo,
    float* __restrict__ qp, float* __restrict__ kp, float* __restrict__ vp) {
  const int z = blockIdx.z;
  float* Cp = (z == 0) ? qp : (z == 1) ? kp : vp;
  gemm_mfma_body(xhi, xlo, whi + (size_t)z * 512 * 512, wlo + (size_t)z * 512 * 512, Cp);
}

__global__ __launch_bounds__(256) void gemm1_mfma_kernel(
    const unsigned short* __restrict__ ahi, const unsigned short* __restrict__ alo,
    const unsigned short* __restrict__ whi, const unsigned short* __restrict__ wlo,
    float* __restrict__ C) {
  gemm_mfma_body(ahi, alo, whi, wlo, C);
}

// ---------------------------------------------------------------------------
// beta = sigmoid(x @ Wb) (float4-vectorized)
// ---------------------------------------------------------------------------
__global__ __launch_bounds__(256) void beta_kernel(const float* __restrict__ x,
                                                   const float* __restrict__ Wb,
                                                   float* __restrict__ beta) {
  int gid = blockIdx.x * blockDim.x + threadIdx.x;
  int bt = gid >> 3, h = gid & 7;
  const float4* xr = (const float4*)(x + (size_t)bt * Dd);
  float s = 0.f;
#pragma unroll 4
  for (int d4 = 0; d4 < Dd / 4; ++d4) {
    float4 xv = xr[d4];
    const float* wb = Wb + (d4 * 4) * Hh + h;
    s = fmaf(xv.x, wb[0 * Hh], s);
    s = fmaf(xv.y, wb[1 * Hh], s);
    s = fmaf(xv.z, wb[2 * Hh], s);
    s = fmaf(xv.w, wb[3 * Hh], s);
  }
  beta[gid] = 1.f / (1.f + expf(-s));
}

// ---------------------------------------------------------------------------
// causal depthwise conv(4) + SiLU (+ optional L2 norm + scale)
// ---------------------------------------------------------------------------
__global__ __launch_bounds__(256) void conv_kernel(
    const float* __restrict__ qp, const float* __restrict__ kp,
    const float* __restrict__ vp,
    const float* __restrict__ cwq, const float* __restrict__ cwk,
    const float* __restrict__ cwv,
    float* __restrict__ qc, float* __restrict__ kc, float* __restrict__ vc) {
  const int mode = blockIdx.z;
  const float* pre; const float* cw; float* post;
  if (mode == 0)      { pre = qp; cw = cwq; post = qc; }
  else if (mode == 1) { pre = kp; cw = cwk; post = kc; }
  else                { pre = vp; cw = cwv; post = vc; }

  const int idx = blockIdx.x * 4 + (threadIdx.x >> 6);
  const int lane = threadIdx.x & 63;
  const int b = idx >> 13;
  const int th = idx & 8191;
  const int t = th >> 3;
  const int h = th & 7;
  const int ch = h * 64 + lane;

  float y = 0.f;
#pragma unroll
  for (int i = 0; i < 4; ++i) {
    int tt = t + i - 3;
    if (tt >= 0)
      y += pre[((size_t)(b * Tt + tt)) * HK + ch] * cw[ch * 4 + i];
  }
  y = y / (1.f + expf(-y));
  if (mode < 2) {
    float ss = reduce64(y * y);
    y *= rsqrtf(ss + 1e-6f);
    if (mode == 0) y *= SCALEc;
  }
  post[((size_t)(b * Tt + t)) * HK + ch] = y;
}

// ---------------------------------------------------------------------------
// sequential IVON delta-rule scan — W=64: one column per wave, lane = k.
//
// R17 model: wall = 1024 x (issue + exposed chain). W16/C4 had issue ~140cy
// (4 cols lockstep in every instr -> no chain hiding from the extra cols)
// while 192 of 256 CUs idled. Here: 1 col/wave, 1 k-elem/lane -> issue ~90cy
// (scalar chain 1-wide; 3 thin LDS reads), reduce64 (6 stages), o/pred-next
// chains interleaved op-by-op (R17-proven). 256 blocks x 4 waves = 1024
// waves = 1/SIMD over ALL 256 CUs.
// Carried-Newton reciprocal + maskless store + tile-top pred retained.
// ---------------------------------------------------------------------------
#define TC 16   // steps per LDS tile

__global__ __launch_bounds__(256) void scan_kernel(
    const float* __restrict__ qc, const float* __restrict__ kc,
    const float* __restrict__ vc, const float* __restrict__ beta,
    float* __restrict__ o) {
  __shared__ float ks[2][TC][64];
  __shared__ float qs[2][TC][64];
  __shared__ float2 vb[2][TC][4];

  const int tid  = threadIdx.x;       // 0..255
  const int lane = tid & 63;          // k index
  const int w    = tid >> 6;          // wave 0..3 = column within block
  const int bid  = blockIdx.x;        // 0..255
  const int vq   = bid >> 4;          // 0..15 (column quad)
  const int bh   = bid & 15;          // bid%8 == bh%8 -> XCD affinity
  const int b = bh >> 3, h = bh & 7;
  const int v  = vq * 4 + w;          // global v column 0..63

  const size_t base2 = ((size_t)b * Tt) * HK + h * 64;
  const float* bp = beta + ((size_t)b * Tt) * Hh + h;
  float* op = o + base2 + v;

  const int sr = tid >> 4;            // staging step row 0..15
  const int sg = tid & 15;            // staging float4 group
  const int vr = tid >> 2;            // v staging row (tid<64)
  const int vcc = tid & 3;            // v staging col 0..3

  // ---- prologue: stage tile 0 into buffer 0 ----
  {
    float4 k4 = *(const float4*)(kc + base2 + (size_t)sr * HK + sg * 4);
    float4 q4 = *(const float4*)(qc + base2 + (size_t)sr * HK + sg * 4);
    *(float4*)&ks[0][sr][sg * 4] = k4;
    *(float4*)&qs[0][sr][sg * 4] = q4;
    if (tid < 64) {
      float vv = vc[base2 + (size_t)vr * HK + vq * 4 + vcc];
      float lb = (0.1f * LRc) * bp[(size_t)vr * Hh];
      vb[0][vr][vcc] = make_float2(vv, lb);
    }
    __syncthreads();
  }

  float S = 0.f, G = 0.f, H = 0.f, r = 1.f;   // r = carried 1/(0.001H+1)

  for (int tile = 0; tile < Tt / TC; ++tile) {
    const int d = tile & 1;
    const int t0 = tile * TC;
    const int more = (tile + 1 < Tt / TC);
    const int tn = more ? t0 + TC : t0;

    // issue next tile's global loads (completion hidden under compute)
    float4 nk = *(const float4*)(kc + base2 + (size_t)(tn + sr) * HK + sg * 4);
    float4 nq = *(const float4*)(qc + base2 + (size_t)(tn + sr) * HK + sg * 4);
    float nv = 0.f, nb = 0.f;
    if (tid < 64) {
      nv = vc[base2 + (size_t)(tn + vr) * HK + vq * 4 + vcc];
      nb = (0.1f * LRc) * bp[(size_t)(tn + vr) * Hh];
    }

    // tile-top pred for step 0 (stalls overlap the load issue above)
    float pred = reduce64(ks[d][0][lane] * S);

#pragma unroll
    for (int s = 0; s < TC; ++s) {
      const float kv = ks[d][s][lane];
      const float qv = qs[d][s][lane];
      const float2 vbc = vb[d][s][w];

      const float diff = pred - vbc.x;
      const float lrb = vbc.y;
      const float gr = kv * diff;
      G = fmaf(B1c, G, gr);
      H = fmaf(B2c, H, gr * gr);
      const float dd = fmaf(H, 0.001f, 1.0f);
      r = r * fmaf(-dd, r, 2.0f);          // carried Newton
      S = fmaf(-lrb, G * r, S);

      float po = qv * S;
      if (s + 1 < TC) {
        float pp = ks[d][s + 1][lane] * S;
        // interleave the two independent 6-stage chains
        po = dpp_add<0xB1>(po);   pp = dpp_add<0xB1>(pp);
        po = dpp_add<0x4E>(po);   pp = dpp_add<0x4E>(pp);
        po = dpp_add<0x141>(po);  pp = dpp_add<0x141>(pp);
        po = dpp_add<0x140>(po);  pp = dpp_add<0x140>(pp);
        po = xor16_add(po);       pp = xor16_add(pp);
        po = xor32_add(po);       pp = xor32_add(pp);
        pred = pp;
      } else {
        po = reduce64(po);
      }
      op[(size_t)(t0 + s) * HK] = po;   // maskless: uniform across wave
    }

    // write next tile into the other buffer; single barrier per tile
    if (more) {
      *(float4*)&ks[d ^ 1][sr][sg * 4] = nk;
      *(float4*)&qs[d ^ 1][sr][sg * 4] = nq;
      if (tid < 64) vb[d ^ 1][vr][vcc] = make_float2(nv, nb);
    }
    __syncthreads();
  }
}

// ---------------------------------------------------------------------------
// RMSNorm over V=64, writes bf16 hi/lo for the MFMA output projection
// ---------------------------------------------------------------------------
__global__ __launch_bounds__(256) void rmsnorm_kernel(
    const float* __restrict__ o, const float* __restrict__ rmsw,
    unsigned short* __restrict__ hi, unsigned short* __restrict__ lo) {
  const int idx = blockIdx.x * 4 + (threadIdx.x >> 6);
  const int lane = threadIdx.x & 63;
  const float* p = o + (size_t)idx * 64;
  float y = p[lane];
  float ss = reduce64(y * y);
  y = y * rsqrtf(ss * (1.f / 64.f) + 1e-5f) * rmsw[lane];
  unsigned short h = f2bf(y);
  hi[(size_t)idx * 64 + lane] = h;
  lo[(size_t)idx * 64 + lane] = f2bf(y - bf2f(h));
}

// ---------------------------------------------------------------------------
extern "C" void kernel_launch(void* const* d_in, const int* in_sizes, int n_in,
                              void* d_out, int out_size, void* d_ws, size_t ws_size,
                              hipStream_t stream) {
  const float* x    = (const float*)d_in[0];
  const float* Wq   = (const float*)d_in[1];
  const float* Wk   = (const float*)d_in[2];
  const float* Wv   = (const float*)d_in[3];
  const float* Wb   = (const float*)d_in[4];
  const float* cwq  = (const float*)d_in[5];
  const float* cwk  = (const float*)d_in[6];
  const float* cwv  = (const float*)d_in[7];
  const float* rmsw = (const float*)d_in[8];
  const float* Wo   = (const float*)d_in[9];
  float* out = (float*)d_out;
  float* ws  = (float*)d_ws;

  const size_t SZ = (size_t)BT * HK;   // 1,048,576 floats
  float* qp   = ws;            // pre-conv q / scan output `on`
  float* kp   = ws + 1 * SZ;   // pre-conv k; dead after conv -> onhi
  float* vp   = ws + 2 * SZ;   // pre-conv v; dead after conv -> onlo
  float* qc   = ws + 3 * SZ;   // conv q; hosts xhi/xlo BEFORE conv
  float* kc   = ws + 4 * SZ;   // conv k; hosts Wqkv hi/lo BEFORE conv
  float* vc   = ws + 5 * SZ;   // conv v; hosts Wo hi/lo AFTER scan
  float* beta = ws + 6 * SZ;   // 16384 floats
  float* on   = qp;

  unsigned short* xhi  = (unsigned short*)qc;
  unsigned short* xlo  = xhi + SZ;
  unsigned short* wh3  = (unsigned short*)kc;
  unsigned short* wl3  = wh3 + 3 * 512 * 512;
  unsigned short* wohi = (unsigned short*)vc;
  unsigned short* wolo = wohi + 512 * 512;
  unsigned short* onhi = (unsigned short*)kp;
  unsigned short* onlo = (unsigned short*)vp;

  // 1. convert x and Wq/Wk/Wv to split-bf16 (W transposed to [n][k])
  cvt_x_kernel<<<dim3(BT * Dd / (256 * 8)), 256, 0, stream>>>(x, xhi, xlo);
  cvt_w_kernel<<<dim3(8, 8, 3), 256, 0, stream>>>(Wq, Wk, Wv, wh3, wl3);
  // 2. projections via MFMA
  gemm3_mfma_kernel<<<dim3(BT / 64, HK / 64, 3), 256, 0, stream>>>(
      xhi, xlo, wh3, wl3, qp, kp, vp);
  // 3. beta
  beta_kernel<<<dim3(BT * Hh / 256), 256, 0, stream>>>(x, Wb, beta);
  // 4. conv + silu + l2norm
  conv_kernel<<<dim3(Bb * Tt * Hh / 4, 1, 3), 256, 0, stream>>>(
      qp, kp, vp, cwq, cwk, cwv, qc, kc, vc);
  // 5. sequential scan: 256 blocks x 4 waves; 1 col/wave, all 256 CUs
  scan_kernel<<<dim3(Bb * Hh * (Vv / 4)), 256, 0, stream>>>(
      qc, kc, vc, beta, on);
  // 6. convert Wo into dead vc slot
  cvt_w_kernel<<<dim3(8, 8, 1), 256, 0, stream>>>(Wo, Wo, Wo, wohi, wolo);
  // 7. RMSNorm -> split-bf16 `on`
  rmsnorm_kernel<<<dim3(Bb * Tt * Hh / 4), 256, 0, stream>>>(on, rmsw, onhi, onlo);
  // 8. output projection via MFMA
  gemm1_mfma_kernel<<<dim3(BT / 64, HK / 64, 1), 256, 0, stream>>>(
      onhi, onlo, wohi, wolo, out);
}